// Round 1
// 281.640 us; speedup vs baseline: 1.0635x; 1.0635x over previous
//
#include <hip/hip_runtime.h>
#include <hip/hip_bf16.h>
#include <stdint.h>

typedef __bf16 bf16;
typedef __bf16 v8bf __attribute__((ext_vector_type(8)));
typedef float  v4f  __attribute__((ext_vector_type(4)));

#define TSEQ   2048
#define HIDDIM 2048
#define NHEAD  16
#define HDIM   128

// async global->LDS, 16B per lane, LDS dest = wave-uniform base + lane*16 (m97 pattern)
__device__ __forceinline__ void async16(void* lds, const void* g)
{
    __builtin_amdgcn_global_load_lds(
        (__attribute__((address_space(1))) void*)(uintptr_t)g,
        (__attribute__((address_space(3))) void*)(unsigned int)(uintptr_t)lds,
        16, 0, 0);
}

// ---------------- f32 -> bf16 bulk convert: 5 matrices of TSEQ*HIDDIM ----------------
__global__ __launch_bounds__(256) void conv5(const float* __restrict__ s0, bf16* __restrict__ d0,
                                             const float* __restrict__ s1, bf16* __restrict__ d1,
                                             const float* __restrict__ s2, bf16* __restrict__ d2,
                                             const float* __restrict__ s3, bf16* __restrict__ d3,
                                             const float* __restrict__ s4, bf16* __restrict__ d4)
{
    const float* src; bf16* dst;
    switch (blockIdx.y) {
        case 0: src = s0; dst = d0; break;
        case 1: src = s1; dst = d1; break;
        case 2: src = s2; dst = d2; break;
        case 3: src = s3; dst = d3; break;
        default: src = s4; dst = d4; break;
    }
    const size_t i = ((size_t)blockIdx.x * 256 + threadIdx.x) * 8;
    const float4 a = *(const float4*)(src + i);
    const float4 b = *(const float4*)(src + i + 4);
    v8bf o;
    o[0] = (bf16)a.x; o[1] = (bf16)a.y; o[2] = (bf16)a.z; o[3] = (bf16)a.w;
    o[4] = (bf16)b.x; o[5] = (bf16)b.y; o[6] = (bf16)b.z; o[7] = (bf16)b.w;
    *(v8bf*)(dst + i) = o;
}

// ------- NT GEMM body: C[M,N] = A[M,K] * B[N,K]^T, 128x128 tile, BK=32 -------
template <typename CT>
__device__ __forceinline__ void gemm_body(const bf16* __restrict__ A,
                                          const bf16* __restrict__ B,
                                          CT* __restrict__ C,
                                          int m0, int n0, int K, int ldc)
{
    __shared__ __attribute__((aligned(16))) bf16 sA[128*32];
    __shared__ __attribute__((aligned(16))) bf16 sB[128*32];
    const int tid  = threadIdx.x;
    const int lane = tid & 63;
    const int w    = tid >> 6;           // wave 0..3
    const int wm   = w >> 1, wn = w & 1; // 2x2 waves of 64x64
    const int quad = lane >> 4, lr = lane & 15;
    const int srow = lane >> 2;          // staging: 16 rows x 4 lanes/row
    const int scol = (lane & 3) * 8;

    const bf16* gA0 = A + (size_t)(m0 + w*32 + srow) * K + scol;
    const bf16* gB0 = B + (size_t)(n0 + w*32 + srow) * K + scol;
    bf16* lA0 = &sA[w*1024];
    bf16* lB0 = &sB[w*1024];

    v4f acc[4][4] = {};

    for (int kt = 0; kt < K; kt += 32) {
        __syncthreads();                         // prev-iter LDS reads done
        async16(lA0,       gA0 + kt);
        async16(lA0 + 512, gA0 + (size_t)16*K + kt);
        async16(lB0,       gB0 + kt);
        async16(lB0 + 512, gB0 + (size_t)16*K + kt);
        __syncthreads();                         // drains vmcnt -> tiles visible
        v8bf a[4], b[4];
#pragma unroll
        for (int i = 0; i < 4; ++i)
            a[i] = *(const v8bf*)&sA[(wm*64 + i*16 + lr)*32 + quad*8];
#pragma unroll
        for (int j = 0; j < 4; ++j)
            b[j] = *(const v8bf*)&sB[(wn*64 + j*16 + lr)*32 + quad*8];
#pragma unroll
        for (int i = 0; i < 4; ++i)
#pragma unroll
            for (int j = 0; j < 4; ++j)
                acc[i][j] = __builtin_amdgcn_mfma_f32_16x16x32_bf16(a[i], b[j], acc[i][j], 0, 0, 0);
    }

#pragma unroll
    for (int i = 0; i < 4; ++i) {
        const int row_b = m0 + wm*64 + i*16 + quad*4;
#pragma unroll
        for (int j = 0; j < 4; ++j) {
            const int col = n0 + wn*64 + j*16 + lr;
#pragma unroll
            for (int r = 0; r < 4; ++r)
                C[(size_t)(row_b + r)*ldc + col] = (CT)acc[i][j][r];
        }
    }
}

__global__ __launch_bounds__(256) void gemm_qkv(const bf16* __restrict__ A,
    const bf16* __restrict__ Wq, const bf16* __restrict__ Wk, const bf16* __restrict__ Wv,
    bf16* __restrict__ qb, bf16* __restrict__ kb, bf16* __restrict__ vb)
{
    const int which = blockIdx.x >> 4;                   // 0:q 1:k 2:v
    const int n0 = (blockIdx.x & 15) * 128;
    const int m0 = blockIdx.y * 128;
    const bf16* B = (which == 0) ? Wq : (which == 1) ? Wk : Wv;
    bf16* C = (which == 0) ? qb : (which == 1) ? kb : vb;
    gemm_body<bf16>(A, B, C, m0, n0, HIDDIM, HIDDIM);
}

// ------- 128x64-tile NT GEMM (fp32 out): 512 blocks -> 2 blocks/CU for overlap -------
__global__ __launch_bounds__(256) void gemm_out(const bf16* __restrict__ A,
    const bf16* __restrict__ B, float* __restrict__ C)
{
    __shared__ __attribute__((aligned(16))) bf16 sA[128*32];
    __shared__ __attribute__((aligned(16))) bf16 sB[64*32];
    const int m0 = blockIdx.y * 128, n0 = blockIdx.x * 64;
    const int K = HIDDIM, ldc = HIDDIM;
    const int tid  = threadIdx.x;
    const int lane = tid & 63;
    const int w    = tid >> 6;           // wave 0..3
    const int wm   = w >> 1, wn = w & 1; // 2x2 waves of 64x32
    const int quad = lane >> 4, lr = lane & 15;
    const int srow = lane >> 2;          // staging: 16 rows x 4 lanes/row
    const int scol = (lane & 3) * 8;

    const bf16* gA0 = A + (size_t)(m0 + w*32 + srow) * K + scol;
    const bf16* gB0 = B + (size_t)(n0 + w*16 + srow) * K + scol;
    bf16* lA0 = &sA[w*1024];
    bf16* lB0 = &sB[w*512];

    v4f acc[4][2] = {};

    for (int kt = 0; kt < K; kt += 32) {
        __syncthreads();
        async16(lA0,       gA0 + kt);
        async16(lA0 + 512, gA0 + (size_t)16*K + kt);
        async16(lB0,       gB0 + kt);
        __syncthreads();
        v8bf a[4], b[2];
#pragma unroll
        for (int i = 0; i < 4; ++i)
            a[i] = *(const v8bf*)&sA[(wm*64 + i*16 + lr)*32 + quad*8];
#pragma unroll
        for (int j = 0; j < 2; ++j)
            b[j] = *(const v8bf*)&sB[(wn*32 + j*16 + lr)*32 + quad*8];
#pragma unroll
        for (int i = 0; i < 4; ++i)
#pragma unroll
            for (int j = 0; j < 2; ++j)
                acc[i][j] = __builtin_amdgcn_mfma_f32_16x16x32_bf16(a[i], b[j], acc[i][j], 0, 0, 0);
    }

#pragma unroll
    for (int i = 0; i < 4; ++i) {
        const int row_b = m0 + wm*64 + i*16 + quad*4;
#pragma unroll
        for (int j = 0; j < 2; ++j) {
            const int col = n0 + wn*32 + j*16 + lr;
#pragma unroll
            for (int r = 0; r < 4; ++r)
                C[(size_t)(row_b + r)*ldc + col] = acc[i][j][r];
        }
    }
}

// ---------------- ReBased feature map: y = LN(x*gamma+beta), q also * D^-0.5 ----------------
__global__ __launch_bounds__(256) void fmap(bf16* __restrict__ qb, bf16* __restrict__ kb,
                                            const float* __restrict__ gamma,
                                            const float* __restrict__ beta)
{
    const int rid  = blockIdx.x * 4 + (threadIdx.x >> 6);   // 0 .. 2*T*H-1
    const int lane = threadIdx.x & 63;
    bf16* base = (rid < TSEQ*NHEAD) ? (qb + (size_t)rid * HDIM)
                                    : (kb + (size_t)(rid - TSEQ*NHEAD) * HDIM);
    const float scale = (rid < TSEQ*NHEAD) ? 0.08838834764831845f : 1.0f; // D^-0.5 on q only

    const bf16 x0b = base[lane*2], x1b = base[lane*2+1];
    const float g0 = gamma[lane*2], g1 = gamma[lane*2+1];
    const float b0 = beta[lane*2],  b1 = beta[lane*2+1];
    float x0 = (float)x0b*g0 + b0;
    float x1 = (float)x1b*g1 + b1;
    float s  = x0 + x1;
    float sq = x0*x0 + x1*x1;
#pragma unroll
    for (int off = 1; off < 64; off <<= 1) { s += __shfl_xor(s, off); sq += __shfl_xor(sq, off); }
    const float mu   = s * (1.0f/128.0f);
    float var        = sq * (1.0f/128.0f) - mu*mu;
    var = fmaxf(var, 0.0f);
    const float rstd = rsqrtf(var + 1e-5f);
    base[lane*2]   = (bf16)((x0 - mu) * rstd * scale);
    base[lane*2+1] = (bf16)((x1 - mu) * rstd * scale);
}

// ---------------- 2048x2048 transpose (vt[c][t] = vb[t][c]) ----------------
__global__ __launch_bounds__(256) void transpose2048(const bf16* __restrict__ src,
                                                     bf16* __restrict__ dst)
{
    __shared__ __attribute__((aligned(16))) bf16 tile[64][72];
    const int t0 = blockIdx.y * 64, c0 = blockIdx.x * 64;
    const int tid = threadIdx.x;
    const int r = tid >> 3;            // 0..31
    const int c = (tid & 7) * 8;       // 0..56
#pragma unroll
    for (int p = 0; p < 2; ++p) {
        const int rr = r + p*32;
        *(v8bf*)&tile[rr][c] = *(const v8bf*)(src + (size_t)(t0+rr)*HIDDIM + c0 + c);
    }
    __syncthreads();
#pragma unroll
    for (int p = 0; p < 2; ++p) {
        const int orow = r + p*32;     // output row = original column
        v8bf o;
#pragma unroll
        for (int i = 0; i < 8; ++i) o[i] = tile[c + i][orow];
        *(v8bf*)(dst + (size_t)(c0+orow)*HIDDIM + t0 + c) = o;
    }
}

// ---------------- quadratic causal attention, paired 64-row q-tiles ----------------
// Balance fix: block handles tiles (31-p) and (p) -> exactly 33 chunks per block.
// grid = 16 pairs x 16 heads = 256 blocks (1/CU), 512 threads = 8 waves.
// Two 4-wave groups process 2 consecutive kv-chunks per iteration (group g ownes
// chunk ich+g, LDS buffer g). Per-wave structure identical to prior version
// (16 q-rows: QK^T -> square/mask -> sS -> PV). Groups hold partial O/z; combined
// through LDS (sO/sZ) once per tile. VGPR prefetch of next chunk-pair overlaps compute.
__global__ __launch_bounds__(512, 2) void attn(const bf16* __restrict__ qb,
                                               const bf16* __restrict__ kb,
                                               const bf16* __restrict__ vt,
                                               bf16* __restrict__ ob)
{
    __shared__ __attribute__((aligned(16))) bf16 sK[2*64*136];   // per-buf [s][d], pad 8
    __shared__ __attribute__((aligned(16))) bf16 sV[2*128*72];   // per-buf [d][s], pad 8
    __shared__ __attribute__((aligned(16))) bf16 sS[2*64*72];    // per-group [q][s], pad 8
    __shared__ __attribute__((aligned(16))) float sO[64*129];    // combine scratch, pad 1
    __shared__ __attribute__((aligned(16))) float sZ[64*17];

    const int h    = blockIdx.y;
    const int pr   = blockIdx.x;              // pair index 0..15
    const int tid  = threadIdx.x, lane = tid & 63;
    const int w    = tid >> 6;                // 0..7
    const int g    = w >> 2;                  // chunk group 0/1
    const int ww   = w & 3;                   // wave within group
    const int quad = lane >> 4, lr = lane & 15;
    const int rs   = tid >> 4;                // staging row 0..31 (x4 passes)
    const int cs   = (tid & 15) * 8;          // staging col 0..120

#pragma unroll
    for (int ti = 0; ti < 2; ++ti) {
        const int tile = ti ? pr : (31 - pr);
        const int nch  = tile + 1;

        // Q fragments (A-layout): wave owns q-rows [tile*64 + ww*16, +16)
        v8bf qa[4];
        {
            const bf16* q0 = qb + (size_t)(tile*64 + ww*16 + lr)*HIDDIM + h*HDIM + quad*8;
#pragma unroll
            for (int ks = 0; ks < 4; ++ks)
                qa[ks] = *(const v8bf*)(q0 + ks*32);
        }

        v4f  o[8] = {};
        float z[4] = {0.f, 0.f, 0.f, 0.f};

        // prefetch chunk-pair (0,1): K rows [0,128), V cols [0,128). Chunk index
        // never exceeds 31 in any staged/prefetched pair (proved: pair-B index
        // <= nch, and ==32 only possible for nch=32 which has no odd tail), so
        // all global reads stay in-bounds; garbage chunks are staged but never computed.
        v8bf curK[4], curV[4], nxtK[4], nxtV[4];
#pragma unroll
        for (int p = 0; p < 4; ++p) {
            curK[p] = *(const v8bf*)(kb + (size_t)(rs + p*32)*HIDDIM + h*HDIM + cs);
            curV[p] = *(const v8bf*)(vt + (size_t)(h*HDIM + rs + p*32)*HIDDIM + cs);
        }

        for (int ich = 0; ich < nch; ich += 2) {
            __syncthreads();                  // prev-iter LDS reads done
#pragma unroll
            for (int p = 0; p < 4; ++p) {
                const int r = rs + p*32;      // kv row within pair [0,128)
                *(v8bf*)&sK[(r>>6)*8704 + (r&63)*136 + cs] = curK[p];
            }
#pragma unroll
            for (int p = 0; p < 4; ++p)       // cs selects buffer (col>=64 -> buf 1)
                *(v8bf*)&sV[(cs>>6)*9216 + (rs + p*32)*72 + (cs & 63)] = curV[p];

            if (ich + 2 < nch) {              // prefetch next pair (overlaps compute)
                const int s1 = (ich + 2) * 64;
#pragma unroll
                for (int p = 0; p < 4; ++p) {
                    nxtK[p] = *(const v8bf*)(kb + (size_t)(s1 + rs + p*32)*HIDDIM + h*HDIM + cs);
                    nxtV[p] = *(const v8bf*)(vt + (size_t)(h*HDIM + rs + p*32)*HIDDIM + s1 + cs);
                }
            }
            __syncthreads();                  // tiles visible

            const int ch = ich + g;
            if (ch < nch) {
                const bf16* sKg = &sK[g*8704];
                const bf16* sVg = &sV[g*9216];
                bf16*       sSg = &sS[g*4608];
                const bool  diag = (ch == tile);
                const int   s0   = ch * 64;

                // QK^T -> square/mask -> z, sS (sS rows wave-private)
                v8bf kbf[4][4];
#pragma unroll
                for (int nj = 0; nj < 4; ++nj)
#pragma unroll
                    for (int ks = 0; ks < 4; ++ks)
                        kbf[nj][ks] = *(const v8bf*)&sKg[(nj*16 + lr)*136 + ks*32 + quad*8];
                const int row_l = ww*16 + quad*4;
                const int qg    = tile*64 + row_l;
#pragma unroll
                for (int nj = 0; nj < 4; ++nj) {
                    v4f s4 = {0.f, 0.f, 0.f, 0.f};
#pragma unroll
                    for (int ks = 0; ks < 4; ++ks)
                        s4 = __builtin_amdgcn_mfma_f32_16x16x32_bf16(qa[ks], kbf[nj][ks], s4, 0, 0, 0);
                    const int col = nj*16 + lr;
                    const int sg  = s0 + col;
#pragma unroll
                    for (int r = 0; r < 4; ++r) {
                        float val = s4[r] * s4[r];
                        if (diag && (sg > qg + r)) val = 0.0f;
                        const bf16 vb16 = (bf16)val;
                        z[r] += (float)vb16;           // consistent with what multiplies V
                        sSg[(row_l + r)*72 + col] = vb16;
                    }
                }

                // O += S * V
#pragma unroll
                for (int ks = 0; ks < 2; ++ks) {
                    const v8bf sa = *(const v8bf*)&sSg[(ww*16 + lr)*72 + ks*32 + quad*8];
#pragma unroll
                    for (int nd = 0; nd < 8; ++nd) {
                        const v8bf vbf = *(const v8bf*)&sVg[(nd*16 + lr)*72 + ks*32 + quad*8];
                        o[nd] = __builtin_amdgcn_mfma_f32_16x16x32_bf16(sa, vbf, o[nd], 0, 0, 0);
                    }
                }
            }

            if (ich + 2 < nch) {
#pragma unroll
                for (int p = 0; p < 4; ++p) { curK[p] = nxtK[p]; curV[p] = nxtV[p]; }
            }
        }

        // cross-group combine: group 1 dumps partial O,z; group 0 adds + epilogue.
        // sO/sZ are disjoint from sK/sV, and group 1's next-tile sO writes sit >=2
        // barriers after group 0's reads here -> no race.
        const int row_l = ww*16 + quad*4;
        __syncthreads();
        if (g == 1) {
#pragma unroll
            for (int nd = 0; nd < 8; ++nd)
#pragma unroll
                for (int r = 0; r < 4; ++r)
                    sO[(row_l + r)*129 + nd*16 + lr] = o[nd][r];
#pragma unroll
            for (int r = 0; r < 4; ++r)
                sZ[(row_l + r)*17 + lr] = z[r];
        }
        __syncthreads();
        if (g == 0) {
#pragma unroll
            for (int nd = 0; nd < 8; ++nd)
#pragma unroll
                for (int r = 0; r < 4; ++r)
                    o[nd][r] += sO[(row_l + r)*129 + nd*16 + lr];
#pragma unroll
            for (int r = 0; r < 4; ++r) {
                float zz = z[r] + sZ[(row_l + r)*17 + lr];
                zz += __shfl_xor(zz, 1); zz += __shfl_xor(zz, 2);
                zz += __shfl_xor(zz, 4); zz += __shfl_xor(zz, 8);
                z[r] = zz + 1e-5f;
            }
            const size_t rbase = (size_t)(tile*64 + row_l)*HIDDIM + h*HDIM;
#pragma unroll
            for (int nd = 0; nd < 8; ++nd) {
                const int col = nd*16 + lr;
#pragma unroll
                for (int r = 0; r < 4; ++r)
                    ob[rbase + (size_t)r*HIDDIM + col] = (bf16)(o[nd][r] / z[r]);
            }
        }
    }
}

extern "C" void kernel_launch(void* const* d_in, const int* in_sizes, int n_in,
                              void* d_out, int out_size, void* d_ws, size_t ws_size,
                              hipStream_t stream)
{
    const float* hs    = (const float*)d_in[0];
    const float* Wq    = (const float*)d_in[1];
    const float* Wk    = (const float*)d_in[2];
    const float* Wv    = (const float*)d_in[3];
    const float* Wo    = (const float*)d_in[4];
    const float* gamma = (const float*)d_in[5];
    const float* beta  = (const float*)d_in[6];
    float* outp = (float*)d_out;

    const size_t MAT = (size_t)TSEQ * HIDDIM;     // 4.19M elems

    // bf16 ws slots (8.39 MB each); Wq_b/Wk_b live in d_out (16.78 MB), dead
    // after gemm_qkv; d_out then becomes the final output. vt aliases hs_b;
    // ob aliases vb.
    bf16* ws   = (bf16*)d_ws;
    bf16* hs_b = ws + 0*MAT;
    bf16* vt   = hs_b;                            // alias: hs_b dead after gemm_qkv
    bf16* Wv_b = ws + 1*MAT;
    bf16* Wo_b = ws + 2*MAT;
    bf16* qb   = ws + 3*MAT;
    bf16* kb   = ws + 4*MAT;
    bf16* vb   = ws + 5*MAT;
    bf16* ob   = vb;                              // alias: vb dead after transpose
    bf16* Wq_b = (bf16*)d_out;
    bf16* Wk_b = (bf16*)d_out + MAT;

    conv5<<<dim3(2048, 5), 256, 0, stream>>>(hs, hs_b, Wq, Wq_b, Wk, Wk_b, Wv, Wv_b, Wo, Wo_b);
    gemm_qkv<<<dim3(48, 16), 256, 0, stream>>>(hs_b, Wq_b, Wk_b, Wv_b, qb, kb, vb);
    fmap<<<dim3(2*TSEQ*NHEAD/4), 256, 0, stream>>>(qb, kb, gamma, beta);
    transpose2048<<<dim3(32, 32), 256, 0, stream>>>(vb, vt);
    attn<<<dim3(16, 16), 512, 0, stream>>>(qb, kb, vt, ob);
    gemm_out<<<dim3(32, 16), 256, 0, stream>>>(ob, Wo_b, outp);
}

// Round 2
// 278.208 us; speedup vs baseline: 1.0766x; 1.0123x over previous
//
#include <hip/hip_runtime.h>
#include <hip/hip_bf16.h>
#include <stdint.h>

typedef __bf16 bf16;
typedef __bf16 v8bf __attribute__((ext_vector_type(8)));
typedef float  v4f  __attribute__((ext_vector_type(4)));

#define TSEQ   2048
#define HIDDIM 2048
#define NHEAD  16
#define HDIM   128

// async global->LDS, 16B per lane, LDS dest = wave-uniform base + lane*16 (m97 pattern)
__device__ __forceinline__ void async16(void* lds, const void* g)
{
    __builtin_amdgcn_global_load_lds(
        (__attribute__((address_space(1))) void*)(uintptr_t)g,
        (__attribute__((address_space(3))) void*)(unsigned int)(uintptr_t)lds,
        16, 0, 0);
}

// ---------------- f32 -> bf16 bulk convert: 5 matrices of TSEQ*HIDDIM ----------------
__global__ __launch_bounds__(256) void conv5(const float* __restrict__ s0, bf16* __restrict__ d0,
                                             const float* __restrict__ s1, bf16* __restrict__ d1,
                                             const float* __restrict__ s2, bf16* __restrict__ d2,
                                             const float* __restrict__ s3, bf16* __restrict__ d3,
                                             const float* __restrict__ s4, bf16* __restrict__ d4)
{
    const float* src; bf16* dst;
    switch (blockIdx.y) {
        case 0: src = s0; dst = d0; break;
        case 1: src = s1; dst = d1; break;
        case 2: src = s2; dst = d2; break;
        case 3: src = s3; dst = d3; break;
        default: src = s4; dst = d4; break;
    }
    const size_t i = ((size_t)blockIdx.x * 256 + threadIdx.x) * 8;
    const float4 a = *(const float4*)(src + i);
    const float4 b = *(const float4*)(src + i + 4);
    v8bf o;
    o[0] = (bf16)a.x; o[1] = (bf16)a.y; o[2] = (bf16)a.z; o[3] = (bf16)a.w;
    o[4] = (bf16)b.x; o[5] = (bf16)b.y; o[6] = (bf16)b.z; o[7] = (bf16)b.w;
    *(v8bf*)(dst + i) = o;
}

// ================= 256x256-tile 8-phase NT GEMM: C = A[M,K] * B[N,K]^T =================
// 512 thr = 8 waves (2M x 4N), per-wave 128x64 out, acc[8][4]. BK=64, double-buffered
// 128 KiB LDS via global_load_lds (linear dest). Bank-deswizzle: 16B slot p in a 128B
// row holds logical slot p ^ (row&7); applied on the global SOURCE at stage time and
// on the LDS read address (both-sides rule). Counted vmcnt(4) only at phases 3/7.

#define PBAR() do { __builtin_amdgcn_sched_barrier(0); __builtin_amdgcn_s_barrier(); \
                    __builtin_amdgcn_sched_barrier(0); } while (0)

// stage one 128-row half (128x64 bf16 = 16KB): 2 loads/thread, wave-uniform LDS base
#define ST(shalf, ghalf) do { \
    async16((shalf) + w*512,        (ghalf) + (size_t)(srow0)*2048); \
    async16((shalf) + 4096 + w*512, (ghalf) + (size_t)(srow0 + 64)*2048); \
} while (0)

// read A-frags for m-half mh of buffer buf into a[0..3][0..1]
#define RD_A(buf, mh) do { _Pragma("unroll") \
    for (int mi_ = 0; mi_ < 4; ++mi_) { \
        const bf16* p_ = &sA[(buf)*16384 + (wm*128 + (mh)*64 + mi_*16 + lr)*64]; \
        a[mi_][0] = *(const v8bf*)(p_ + c0); \
        a[mi_][1] = *(const v8bf*)(p_ + c1); } } while (0)

// read B-frags for n-half nh of buffer buf into b[nh*2 .. nh*2+1][0..1]
#define RD_B(buf, nh) do { _Pragma("unroll") \
    for (int nj_ = 0; nj_ < 2; ++nj_) { \
        const bf16* p_ = &sB[(buf)*16384 + (wn*64 + (nh)*32 + nj_*16 + lr)*64]; \
        b[(nh)*2+nj_][0] = *(const v8bf*)(p_ + c0); \
        b[(nh)*2+nj_][1] = *(const v8bf*)(p_ + c1); } } while (0)

// one C-quadrant: 16 MFMA (4m x 2n x 2k), m-half mh (regs a), n-half nh (regs b)
#define MQ(mh, nh) do { _Pragma("unroll") \
    for (int mi_ = 0; mi_ < 4; ++mi_) { _Pragma("unroll") \
        for (int nj_ = 0; nj_ < 2; ++nj_) { \
            acc[(mh)*4+mi_][(nh)*2+nj_] = __builtin_amdgcn_mfma_f32_16x16x32_bf16( \
                a[mi_][0], b[(nh)*2+nj_][0], acc[(mh)*4+mi_][(nh)*2+nj_], 0, 0, 0); \
            acc[(mh)*4+mi_][(nh)*2+nj_] = __builtin_amdgcn_mfma_f32_16x16x32_bf16( \
                a[mi_][1], b[(nh)*2+nj_][1], acc[(mh)*4+mi_][(nh)*2+nj_], 0, 0, 0); \
        } } } while (0)

__global__ __launch_bounds__(512, 2) void gemm_qkv8(const bf16* __restrict__ A,
    const bf16* __restrict__ Wq, const bf16* __restrict__ Wk, const bf16* __restrict__ Wv,
    bf16* __restrict__ qb, bf16* __restrict__ kb, bf16* __restrict__ vb)
{
    __shared__ __attribute__((aligned(16))) bf16 sA[2*16384];   // 64 KB
    __shared__ __attribute__((aligned(16))) bf16 sB[2*16384];   // 64 KB
    const int which = blockIdx.x >> 3;                // 0:q 1:k 2:v
    const int n0 = (blockIdx.x & 7) * 256;
    const int m0 = blockIdx.y * 256;
    const bf16* B = (which == 0) ? Wq : (which == 1) ? Wk : Wv;
    bf16* C = (which == 0) ? qb : (which == 1) ? kb : vb;

    const int tid  = threadIdx.x, l = tid & 63, w = tid >> 6;   // 8 waves
    const int wm   = w >> 2, wn = w & 3;                        // 2x4 wave grid
    const int quad = l >> 4, lr = l & 15;
    // staging geometry: lane covers phys (row = w*8 + l>>3, slot = l&7); its global
    // source column block = slot ^ (row&7)  (row&7 == (l>>3)&7 for all halves)
    const int srow0 = w*8 + (l>>3);
    const int scol  = ((l & 7) ^ ((l >> 3) & 7)) * 8;
    // read-side deswizzle: logical k-block (kk*4+quad) lives at phys slot ^(row&7),
    // row&7 == lr&7 for every fragment row
    const int c0 = (( quad     ) ^ (lr & 7)) * 8;
    const int c1 = ((quad + 4  ) ^ (lr & 7)) * 8;

    const bf16* Ag = A + (size_t)m0 * 2048 + scol;
    const bf16* Bg = B + (size_t)n0 * 2048 + scol;

    v4f  acc[8][4] = {};
    v8bf a[4][2], b[4][2];

    // prologue: A(0) h0,h1; B(0) h0,h1; B(1) h0,h1  -> vmcnt(4) leaves B(1) in flight
    ST(&sA[0],          Ag);
    ST(&sA[8192],       Ag + (size_t)128*2048);
    ST(&sB[0],          Bg);
    ST(&sB[8192],       Bg + (size_t)128*2048);
    ST(&sB[16384],      Bg + 64);
    ST(&sB[16384+8192], Bg + (size_t)128*2048 + 64);
    asm volatile("s_waitcnt vmcnt(4)" ::: "memory");
    __builtin_amdgcn_s_barrier();
    __builtin_amdgcn_sched_barrier(0);

#pragma unroll 1
    for (int it = 0; it < 16; ++it) {                 // tiles t0=2it (buf0), t1 (buf1)
        const int k1 = it*128 + 64;
        const int k2 = (it*128 + 128) & 2047;         // wraps harmlessly on last iter
        const int k3 = (it*128 + 192) & 2047;

        // Ph0: read aL,bL(buf0); stage A(t1)h0 -> buf1
        RD_A(0, 0); RD_B(0, 0);
        ST(&sA[16384], Ag + k1);
        PBAR(); __builtin_amdgcn_s_setprio(1); MQ(0, 0); __builtin_amdgcn_s_setprio(0); PBAR();
        // Ph1: read bH(buf0); stage A(t1)h1 -> buf1
        RD_B(0, 1);
        ST(&sA[16384+8192], Ag + (size_t)128*2048 + k1);
        PBAR(); __builtin_amdgcn_s_setprio(1); MQ(0, 1); __builtin_amdgcn_s_setprio(0); PBAR();
        // Ph2: read aH(buf0); stage B(t0+2)h0 -> buf0 (buf0-B free after Ph1)
        RD_A(0, 1);
        ST(&sB[0], Bg + k2);
        PBAR(); __builtin_amdgcn_s_setprio(1); MQ(1, 0); __builtin_amdgcn_s_setprio(0); PBAR();
        // Ph3: stage B(t0+2)h1; counted wait -> tile t1 fully landed
        ST(&sB[8192], Bg + (size_t)128*2048 + k2);
        asm volatile("s_waitcnt vmcnt(4)" ::: "memory");
        PBAR(); __builtin_amdgcn_s_setprio(1); MQ(1, 1); __builtin_amdgcn_s_setprio(0); PBAR();
        // Ph4: read aL,bL(buf1); stage A(t0+2)h0 -> buf0 (buf0-A free after Ph2)
        RD_A(1, 0); RD_B(1, 0);
        ST(&sA[0], Ag + k2);
        PBAR(); __builtin_amdgcn_s_setprio(1); MQ(0, 0); __builtin_amdgcn_s_setprio(0); PBAR();
        // Ph5: read bH(buf1); stage A(t0+2)h1 -> buf0
        RD_B(1, 1);
        ST(&sA[8192], Ag + (size_t)128*2048 + k2);
        PBAR(); __builtin_amdgcn_s_setprio(1); MQ(0, 1); __builtin_amdgcn_s_setprio(0); PBAR();
        // Ph6: read aH(buf1); stage B(t0+3)h0 -> buf1 (buf1-B free after Ph5)
        RD_A(1, 1);
        ST(&sB[16384], Bg + k3);
        PBAR(); __builtin_amdgcn_s_setprio(1); MQ(1, 0); __builtin_amdgcn_s_setprio(0); PBAR();
        // Ph7: stage B(t0+3)h1; counted wait -> tile t0+2 fully landed
        ST(&sB[16384+8192], Bg + (size_t)128*2048 + k3);
        asm volatile("s_waitcnt vmcnt(4)" ::: "memory");
        PBAR(); __builtin_amdgcn_s_setprio(1); MQ(1, 1); __builtin_amdgcn_s_setprio(0); PBAR();
    }

    // epilogue: acc[mh*4+mi][nh*2+nj] -> rows wm*128 + mh*64 + mi*16, cols wn*64 + nh*32 + nj*16
#pragma unroll
    for (int mi = 0; mi < 8; ++mi) {
        const int row = m0 + wm*128 + (mi >> 2)*64 + (mi & 3)*16 + quad*4;
#pragma unroll
        for (int nj = 0; nj < 4; ++nj) {
            const int col = n0 + wn*64 + (nj >> 1)*32 + (nj & 1)*16 + lr;
#pragma unroll
            for (int r = 0; r < 4; ++r)
                C[(size_t)(row + r)*2048 + col] = (bf16)acc[mi][nj][r];
        }
    }
}

// ------- 128x64-tile NT GEMM (fp32 out): 512 blocks -> 2 blocks/CU for overlap -------
__global__ __launch_bounds__(256) void gemm_out(const bf16* __restrict__ A,
    const bf16* __restrict__ B, float* __restrict__ C)
{
    __shared__ __attribute__((aligned(16))) bf16 sA[128*32];
    __shared__ __attribute__((aligned(16))) bf16 sB[64*32];
    const int m0 = blockIdx.y * 128, n0 = blockIdx.x * 64;
    const int K = HIDDIM, ldc = HIDDIM;
    const int tid  = threadIdx.x;
    const int lane = tid & 63;
    const int w    = tid >> 6;           // wave 0..3
    const int wm   = w >> 1, wn = w & 1; // 2x2 waves of 64x32
    const int quad = lane >> 4, lr = lane & 15;
    const int srow = lane >> 2;          // staging: 16 rows x 4 lanes/row
    const int scol = (lane & 3) * 8;

    const bf16* gA0 = A + (size_t)(m0 + w*32 + srow) * K + scol;
    const bf16* gB0 = B + (size_t)(n0 + w*16 + srow) * K + scol;
    bf16* lA0 = &sA[w*1024];
    bf16* lB0 = &sB[w*512];

    v4f acc[4][2] = {};

    for (int kt = 0; kt < K; kt += 32) {
        __syncthreads();
        async16(lA0,       gA0 + kt);
        async16(lA0 + 512, gA0 + (size_t)16*K + kt);
        async16(lB0,       gB0 + kt);
        __syncthreads();
        v8bf a[4], b[2];
#pragma unroll
        for (int i = 0; i < 4; ++i)
            a[i] = *(const v8bf*)&sA[(wm*64 + i*16 + lr)*32 + quad*8];
#pragma unroll
        for (int j = 0; j < 2; ++j)
            b[j] = *(const v8bf*)&sB[(wn*32 + j*16 + lr)*32 + quad*8];
#pragma unroll
        for (int i = 0; i < 4; ++i)
#pragma unroll
            for (int j = 0; j < 2; ++j)
                acc[i][j] = __builtin_amdgcn_mfma_f32_16x16x32_bf16(a[i], b[j], acc[i][j], 0, 0, 0);
    }

#pragma unroll
    for (int i = 0; i < 4; ++i) {
        const int row_b = m0 + wm*64 + i*16 + quad*4;
#pragma unroll
        for (int j = 0; j < 2; ++j) {
            const int col = n0 + wn*32 + j*16 + lr;
#pragma unroll
            for (int r = 0; r < 4; ++r)
                C[(size_t)(row_b + r)*ldc + col] = acc[i][j][r];
        }
    }
}

// ---------------- ReBased feature map: y = LN(x*gamma+beta), q also * D^-0.5 ----------------
__global__ __launch_bounds__(256) void fmap(bf16* __restrict__ qb, bf16* __restrict__ kb,
                                            const float* __restrict__ gamma,
                                            const float* __restrict__ beta)
{
    const int rid  = blockIdx.x * 4 + (threadIdx.x >> 6);   // 0 .. 2*T*H-1
    const int lane = threadIdx.x & 63;
    bf16* base = (rid < TSEQ*NHEAD) ? (qb + (size_t)rid * HDIM)
                                    : (kb + (size_t)(rid - TSEQ*NHEAD) * HDIM);
    const float scale = (rid < TSEQ*NHEAD) ? 0.08838834764831845f : 1.0f; // D^-0.5 on q only

    const bf16 x0b = base[lane*2], x1b = base[lane*2+1];
    const float g0 = gamma[lane*2], g1 = gamma[lane*2+1];
    const float b0 = beta[lane*2],  b1 = beta[lane*2+1];
    float x0 = (float)x0b*g0 + b0;
    float x1 = (float)x1b*g1 + b1;
    float s  = x0 + x1;
    float sq = x0*x0 + x1*x1;
#pragma unroll
    for (int off = 1; off < 64; off <<= 1) { s += __shfl_xor(s, off); sq += __shfl_xor(sq, off); }
    const float mu   = s * (1.0f/128.0f);
    float var        = sq * (1.0f/128.0f) - mu*mu;
    var = fmaxf(var, 0.0f);
    const float rstd = rsqrtf(var + 1e-5f);
    base[lane*2]   = (bf16)((x0 - mu) * rstd * scale);
    base[lane*2+1] = (bf16)((x1 - mu) * rstd * scale);
}

// ---------------- 2048x2048 transpose (vt[c][t] = vb[t][c]) ----------------
__global__ __launch_bounds__(256) void transpose2048(const bf16* __restrict__ src,
                                                     bf16* __restrict__ dst)
{
    __shared__ __attribute__((aligned(16))) bf16 tile[64][72];
    const int t0 = blockIdx.y * 64, c0 = blockIdx.x * 64;
    const int tid = threadIdx.x;
    const int r = tid >> 3;            // 0..31
    const int c = (tid & 7) * 8;       // 0..56
#pragma unroll
    for (int p = 0; p < 2; ++p) {
        const int rr = r + p*32;
        *(v8bf*)&tile[rr][c] = *(const v8bf*)(src + (size_t)(t0+rr)*HIDDIM + c0 + c);
    }
    __syncthreads();
#pragma unroll
    for (int p = 0; p < 2; ++p) {
        const int orow = r + p*32;     // output row = original column
        v8bf o;
#pragma unroll
        for (int i = 0; i < 8; ++i) o[i] = tile[c + i][orow];
        *(v8bf*)(dst + (size_t)(c0+orow)*HIDDIM + t0 + c) = o;
    }
}

// ---------------- quadratic causal attention, paired 64-row q-tiles ----------------
// Balance fix: block handles tiles (31-p) and (p) -> exactly 33 chunks per block.
// grid = 16 pairs x 16 heads = 256 blocks (1/CU), 512 threads = 8 waves.
__global__ __launch_bounds__(512, 2) void attn(const bf16* __restrict__ qb,
                                               const bf16* __restrict__ kb,
                                               const bf16* __restrict__ vt,
                                               bf16* __restrict__ ob)
{
    __shared__ __attribute__((aligned(16))) bf16 sK[2*64*136];   // per-buf [s][d], pad 8
    __shared__ __attribute__((aligned(16))) bf16 sV[2*128*72];   // per-buf [d][s], pad 8
    __shared__ __attribute__((aligned(16))) bf16 sS[2*64*72];    // per-group [q][s], pad 8
    __shared__ __attribute__((aligned(16))) float sO[64*129];    // combine scratch, pad 1
    __shared__ __attribute__((aligned(16))) float sZ[64*17];

    const int h    = blockIdx.y;
    const int pr   = blockIdx.x;              // pair index 0..15
    const int tid  = threadIdx.x, lane = tid & 63;
    const int w    = tid >> 6;                // 0..7
    const int g    = w >> 2;                  // chunk group 0/1
    const int ww   = w & 3;                   // wave within group
    const int quad = lane >> 4, lr = lane & 15;
    const int rs   = tid >> 4;                // staging row 0..31 (x4 passes)
    const int cs   = (tid & 15) * 8;          // staging col 0..120

#pragma unroll
    for (int ti = 0; ti < 2; ++ti) {
        const int tile = ti ? pr : (31 - pr);
        const int nch  = tile + 1;

        // Q fragments (A-layout): wave owns q-rows [tile*64 + ww*16, +16)
        v8bf qa[4];
        {
            const bf16* q0 = qb + (size_t)(tile*64 + ww*16 + lr)*HIDDIM + h*HDIM + quad*8;
#pragma unroll
            for (int ks = 0; ks < 4; ++ks)
                qa[ks] = *(const v8bf*)(q0 + ks*32);
        }

        v4f  o[8] = {};
        float z[4] = {0.f, 0.f, 0.f, 0.f};

        v8bf curK[4], curV[4], nxtK[4], nxtV[4];
#pragma unroll
        for (int p = 0; p < 4; ++p) {
            curK[p] = *(const v8bf*)(kb + (size_t)(rs + p*32)*HIDDIM + h*HDIM + cs);
            curV[p] = *(const v8bf*)(vt + (size_t)(h*HDIM + rs + p*32)*HIDDIM + cs);
        }

        for (int ich = 0; ich < nch; ich += 2) {
            __syncthreads();                  // prev-iter LDS reads done
#pragma unroll
            for (int p = 0; p < 4; ++p) {
                const int r = rs + p*32;      // kv row within pair [0,128)
                *(v8bf*)&sK[(r>>6)*8704 + (r&63)*136 + cs] = curK[p];
            }
#pragma unroll
            for (int p = 0; p < 4; ++p)       // cs selects buffer (col>=64 -> buf 1)
                *(v8bf*)&sV[(cs>>6)*9216 + (rs + p*32)*72 + (cs & 63)] = curV[p];

            if (ich + 2 < nch) {              // prefetch next pair (overlaps compute)
                const int s1 = (ich + 2) * 64;
#pragma unroll
                for (int p = 0; p < 4; ++p) {
                    nxtK[p] = *(const v8bf*)(kb + (size_t)(s1 + rs + p*32)*HIDDIM + h*HDIM + cs);
                    nxtV[p] = *(const v8bf*)(vt + (size_t)(h*HDIM + rs + p*32)*HIDDIM + s1 + cs);
                }
            }
            __syncthreads();                  // tiles visible

            const int ch = ich + g;
            if (ch < nch) {
                const bf16* sKg = &sK[g*8704];
                const bf16* sVg = &sV[g*9216];
                bf16*       sSg = &sS[g*4608];
                const bool  diag = (ch == tile);
                const int   s0   = ch * 64;

                // QK^T -> square/mask -> z, sS (sS rows wave-private)
                v8bf kbf[4][4];
#pragma unroll
                for (int nj = 0; nj < 4; ++nj)
#pragma unroll
                    for (int ks = 0; ks < 4; ++ks)
                        kbf[nj][ks] = *(const v8bf*)&sKg[(nj*16 + lr)*136 + ks*32 + quad*8];
                const int row_l = ww*16 + quad*4;
                const int qg    = tile*64 + row_l;
#pragma unroll
                for (int nj = 0; nj < 4; ++nj) {
                    v4f s4 = {0.f, 0.f, 0.f, 0.f};
#pragma unroll
                    for (int ks = 0; ks < 4; ++ks)
                        s4 = __builtin_amdgcn_mfma_f32_16x16x32_bf16(qa[ks], kbf[nj][ks], s4, 0, 0, 0);
                    const int col = nj*16 + lr;
                    const int sg  = s0 + col;
#pragma unroll
                    for (int r = 0; r < 4; ++r) {
                        float val = s4[r] * s4[r];
                        if (diag && (sg > qg + r)) val = 0.0f;
                        const bf16 vb16 = (bf16)val;
                        z[r] += (float)vb16;           // consistent with what multiplies V
                        sSg[(row_l + r)*72 + col] = vb16;
                    }
                }

                // O += S * V
#pragma unroll
                for (int ks = 0; ks < 2; ++ks) {
                    const v8bf sa = *(const v8bf*)&sSg[(ww*16 + lr)*72 + ks*32 + quad*8];
#pragma unroll
                    for (int nd = 0; nd < 8; ++nd) {
                        const v8bf vbf = *(const v8bf*)&sVg[(nd*16 + lr)*72 + ks*32 + quad*8];
                        o[nd] = __builtin_amdgcn_mfma_f32_16x16x32_bf16(sa, vbf, o[nd], 0, 0, 0);
                    }
                }
            }

            if (ich + 2 < nch) {
#pragma unroll
                for (int p = 0; p < 4; ++p) { curK[p] = nxtK[p]; curV[p] = nxtV[p]; }
            }
        }

        // cross-group combine: group 1 dumps partial O,z; group 0 adds + epilogue.
        const int row_l = ww*16 + quad*4;
        __syncthreads();
        if (g == 1) {
#pragma unroll
            for (int nd = 0; nd < 8; ++nd)
#pragma unroll
                for (int r = 0; r < 4; ++r)
                    sO[(row_l + r)*129 + nd*16 + lr] = o[nd][r];
#pragma unroll
            for (int r = 0; r < 4; ++r)
                sZ[(row_l + r)*17 + lr] = z[r];
        }
        __syncthreads();
        if (g == 0) {
#pragma unroll
            for (int nd = 0; nd < 8; ++nd)
#pragma unroll
                for (int r = 0; r < 4; ++r)
                    o[nd][r] += sO[(row_l + r)*129 + nd*16 + lr];
#pragma unroll
            for (int r = 0; r < 4; ++r) {
                float zz = z[r] + sZ[(row_l + r)*17 + lr];
                zz += __shfl_xor(zz, 1); zz += __shfl_xor(zz, 2);
                zz += __shfl_xor(zz, 4); zz += __shfl_xor(zz, 8);
                z[r] = zz + 1e-5f;
            }
            const size_t rbase = (size_t)(tile*64 + row_l)*HIDDIM + h*HDIM;
#pragma unroll
            for (int nd = 0; nd < 8; ++nd) {
                const int col = nd*16 + lr;
#pragma unroll
                for (int r = 0; r < 4; ++r)
                    ob[rbase + (size_t)r*HIDDIM + col] = (bf16)(o[nd][r] / z[r]);
            }
        }
    }
}

extern "C" void kernel_launch(void* const* d_in, const int* in_sizes, int n_in,
                              void* d_out, int out_size, void* d_ws, size_t ws_size,
                              hipStream_t stream)
{
    const float* hs    = (const float*)d_in[0];
    const float* Wq    = (const float*)d_in[1];
    const float* Wk    = (const float*)d_in[2];
    const float* Wv    = (const float*)d_in[3];
    const float* Wo    = (const float*)d_in[4];
    const float* gamma = (const float*)d_in[5];
    const float* beta  = (const float*)d_in[6];
    float* outp = (float*)d_out;

    const size_t MAT = (size_t)TSEQ * HIDDIM;     // 4.19M elems

    // bf16 ws slots (8.39 MB each); Wq_b/Wk_b live in d_out (16.78 MB), dead
    // after gemm_qkv; d_out then becomes the final output. vt aliases hs_b;
    // ob aliases vb.
    bf16* ws   = (bf16*)d_ws;
    bf16* hs_b = ws + 0*MAT;
    bf16* vt   = hs_b;                            // alias: hs_b dead after gemm_qkv
    bf16* Wv_b = ws + 1*MAT;
    bf16* Wo_b = ws + 2*MAT;
    bf16* qb   = ws + 3*MAT;
    bf16* kb   = ws + 4*MAT;
    bf16* vb   = ws + 5*MAT;
    bf16* ob   = vb;                              // alias: vb dead after transpose
    bf16* Wq_b = (bf16*)d_out;
    bf16* Wk_b = (bf16*)d_out + MAT;

    conv5<<<dim3(2048, 5), 256, 0, stream>>>(hs, hs_b, Wq, Wq_b, Wk, Wk_b, Wv, Wv_b, Wo, Wo_b);
    gemm_qkv8<<<dim3(24, 8), 512, 0, stream>>>(hs_b, Wq_b, Wk_b, Wv_b, qb, kb, vb);
    fmap<<<dim3(2*TSEQ*NHEAD/4), 256, 0, stream>>>(qb, kb, gamma, beta);
    transpose2048<<<dim3(32, 32), 256, 0, stream>>>(vb, vt);
    attn<<<dim3(16, 16), 512, 0, stream>>>(qb, kb, vt, ob);
    gemm_out<<<dim3(32, 16), 256, 0, stream>>>(ob, Wo_b, outp);
}

// Round 3
// 272.943 us; speedup vs baseline: 1.0974x; 1.0193x over previous
//
#include <hip/hip_runtime.h>
#include <hip/hip_bf16.h>
#include <stdint.h>

typedef __bf16 bf16;
typedef __bf16 v8bf __attribute__((ext_vector_type(8)));
typedef float  v4f  __attribute__((ext_vector_type(4)));

#define TSEQ   2048
#define HIDDIM 2048
#define NHEAD  16
#define HDIM   128

// async global->LDS, 16B per lane, LDS dest = wave-uniform base + lane*16 (m97 pattern)
__device__ __forceinline__ void async16(void* lds, const void* g)
{
    __builtin_amdgcn_global_load_lds(
        (__attribute__((address_space(1))) void*)(uintptr_t)g,
        (__attribute__((address_space(3))) void*)(unsigned int)(uintptr_t)lds,
        16, 0, 0);
}

// ---------------- f32 -> bf16 bulk convert: 5 matrices of TSEQ*HIDDIM ----------------
__global__ __launch_bounds__(256) void conv5(const float* __restrict__ s0, bf16* __restrict__ d0,
                                             const float* __restrict__ s1, bf16* __restrict__ d1,
                                             const float* __restrict__ s2, bf16* __restrict__ d2,
                                             const float* __restrict__ s3, bf16* __restrict__ d3,
                                             const float* __restrict__ s4, bf16* __restrict__ d4)
{
    const float* src; bf16* dst;
    switch (blockIdx.y) {
        case 0: src = s0; dst = d0; break;
        case 1: src = s1; dst = d1; break;
        case 2: src = s2; dst = d2; break;
        case 3: src = s3; dst = d3; break;
        default: src = s4; dst = d4; break;
    }
    const size_t i = ((size_t)blockIdx.x * 256 + threadIdx.x) * 8;
    const float4 a = *(const float4*)(src + i);
    const float4 b = *(const float4*)(src + i + 4);
    v8bf o;
    o[0] = (bf16)a.x; o[1] = (bf16)a.y; o[2] = (bf16)a.z; o[3] = (bf16)a.w;
    o[4] = (bf16)b.x; o[5] = (bf16)b.y; o[6] = (bf16)b.z; o[7] = (bf16)b.w;
    *(v8bf*)(dst + i) = o;
}

// ============ 256x192-tile 4-phase NT GEMM: C[2048,6144] = A * Wcat^T ============
// Grid 32x8 = 256 blocks = 1/CU (full chip). 512 thr = 8 waves (2M x 4N), per-wave
// 128x48, acc[8][3]. BK=64, double-buffered 112 KiB LDS via global_load_lds (linear
// dest). Bank-deswizzle: 16B slot p of a 128B row holds logical slot p ^ (row&7),
// applied on the global SOURCE and on the LDS read address (both-sides rule).
// 4 phases/iter x 24 MFMA; counted vmcnt only (never 0 in loop), >=2-phase depth.

#define PBAR() do { __builtin_amdgcn_sched_barrier(0); __builtin_amdgcn_s_barrier(); \
                    __builtin_amdgcn_sched_barrier(0); } while (0)

// stage full A-tile (256x64, 4 steps) / B-tile (192x64, 3 steps) into buffer
#define STA(buf, ka) do { _Pragma("unroll") \
    for (int s_ = 0; s_ < 4; ++s_) \
        async16(&sA[(buf)*16384 + s_*4096 + w*512], \
                Ag + (ka) + (size_t)(s_*64 + w*8 + (l>>3))*2048); } while (0)
#define STB(buf, ka) do { _Pragma("unroll") \
    for (int s_ = 0; s_ < 3; ++s_) \
        async16(&sB[(buf)*12288 + s_*4096 + w*512], \
                Bg + (ka) + (size_t)(s_*64 + w*8 + (l>>3))*2048); } while (0)

#define RDA(buf, mh) do { _Pragma("unroll") \
    for (int mi_ = 0; mi_ < 4; ++mi_) { \
        const bf16* p_ = &sA[(buf)*16384 + (wm*128 + (mh)*64 + mi_*16 + lr)*64]; \
        a[mi_][0] = *(const v8bf*)(p_ + c0); \
        a[mi_][1] = *(const v8bf*)(p_ + c1); } } while (0)
#define RDB(buf) do { _Pragma("unroll") \
    for (int nj_ = 0; nj_ < 3; ++nj_) { \
        const bf16* p_ = &sB[(buf)*12288 + (wn*48 + nj_*16 + lr)*64]; \
        b[nj_][0] = *(const v8bf*)(p_ + c0); \
        b[nj_][1] = *(const v8bf*)(p_ + c1); } } while (0)

#define MQ24(mh) do { _Pragma("unroll") \
    for (int mi_ = 0; mi_ < 4; ++mi_) { _Pragma("unroll") \
        for (int nj_ = 0; nj_ < 3; ++nj_) { \
            acc[(mh)*4+mi_][nj_] = __builtin_amdgcn_mfma_f32_16x16x32_bf16( \
                a[mi_][0], b[nj_][0], acc[(mh)*4+mi_][nj_], 0, 0, 0); \
            acc[(mh)*4+mi_][nj_] = __builtin_amdgcn_mfma_f32_16x16x32_bf16( \
                a[mi_][1], b[nj_][1], acc[(mh)*4+mi_][nj_], 0, 0, 0); \
        } } } while (0)

__global__ __launch_bounds__(512, 2) void gemm_qkv192(const bf16* __restrict__ A,
    const bf16* __restrict__ Wcat, bf16* __restrict__ qb, bf16* __restrict__ kb,
    bf16* __restrict__ vb)
{
    __shared__ __attribute__((aligned(16))) bf16 sA[2*16384];   // 2 x 256x64 = 64 KB
    __shared__ __attribute__((aligned(16))) bf16 sB[2*12288];   // 2 x 192x64 = 48 KB
    const int n0g = blockIdx.x * 192;         // 0..6143 over concat(Wq,Wk,Wv) rows
    const int m0  = blockIdx.y * 256;

    const int tid = threadIdx.x, l = tid & 63, w = tid >> 6;    // 8 waves
    const int wm = w >> 2, wn = w & 3;                          // 2x4 wave grid
    const int quad = l >> 4, lr = l & 15;
    // staging: lane covers phys (row = w*8 + l>>3, slot = l&7); global source
    // col-block = slot ^ (row&7). read-side: logical k-block j at phys j^(lr&7).
    const int scol = ((l & 7) ^ ((l >> 3) & 7)) * 8;
    const int c0 = ((quad    ) ^ (lr & 7)) * 8;
    const int c1 = ((quad + 4) ^ (lr & 7)) * 8;

    const bf16* Ag = A    + (size_t)m0  * 2048 + scol;
    const bf16* Bg = Wcat + (size_t)n0g * 2048 + scol;

    v4f  acc[8][3] = {};
    v8bf a[4][2], b[3][2];

    // prologue: A(0),B(0) -> buf0; B(1),A(1) -> buf1. vmcnt(7) drains tile 0,
    // leaves tile 1's 7 loads in flight (steady-state invariant entering Ph0).
    STA(0, 0); STB(0, 0);
    STB(1, 64); STA(1, 64);
    asm volatile("s_waitcnt vmcnt(7)" ::: "memory");
    __builtin_amdgcn_s_barrier();
    __builtin_amdgcn_sched_barrier(0);

#pragma unroll 1
    for (int it = 0; it < 16; ++it) {
        const int k2 = (it*128 + 128) & 2047;  // tile T0+2 (wrap harmless last iter)
        const int k3 = (it*128 + 192) & 2047;  // tiles T0+3 (B) and next-T1 (A)

        // Ph0: regs from buf0 (T0); no staging
        RDB(0); RDA(0, 0);
        PBAR(); __builtin_amdgcn_s_setprio(1); MQ24(0); __builtin_amdgcn_s_setprio(0); PBAR();
        // Ph1: finish buf0 reads; stage B(T0+2)->buf0-B; wait: tile T1 landed
        RDA(0, 1);
        STB(0, k2);
        PBAR(); __builtin_amdgcn_s_setprio(1); MQ24(1); __builtin_amdgcn_s_setprio(0);
        asm volatile("s_waitcnt vmcnt(3)" ::: "memory");
        PBAR();
        // Ph2: regs from buf1 (T1); stage A(T0+2)->buf0-A
        RDB(1); RDA(1, 0);
        STA(0, k2);
        PBAR(); __builtin_amdgcn_s_setprio(1); MQ24(0); __builtin_amdgcn_s_setprio(0); PBAR();
        // Ph3: finish buf1 reads; stage B+A(T0+3 = next iter's T1)->buf1;
        // wait: tile T0+2 landed (7 oldest of 14) before next Ph0 reads buf0
        RDA(1, 1);
        STB(1, k3); STA(1, k3);
        PBAR(); __builtin_amdgcn_s_setprio(1); MQ24(1); __builtin_amdgcn_s_setprio(0);
        asm volatile("s_waitcnt vmcnt(7)" ::: "memory");
        PBAR();
    }
    asm volatile("s_waitcnt vmcnt(0)" ::: "memory");   // drain wrap refetches

    // epilogue: row = wm*128 + (mi>>2)*64 + (mi&3)*16 + quad*4; col block -> q/k/v
    // by colg>>11 (16-col blocks never straddle the 2048-aligned boundary)
#pragma unroll
    for (int mi = 0; mi < 8; ++mi) {
        const int row = m0 + wm*128 + (mi >> 2)*64 + (mi & 3)*16 + quad*4;
#pragma unroll
        for (int nj = 0; nj < 3; ++nj) {
            const int colg  = n0g + wn*48 + nj*16;
            const int which = colg >> 11;
            bf16* Cb = (which == 0) ? qb : (which == 1) ? kb : vb;
            const int lcol = (colg & 2047) + lr;
#pragma unroll
            for (int r = 0; r < 4; ++r)
                Cb[(size_t)(row + r)*2048 + lcol] = (bf16)acc[mi][nj][r];
        }
    }
}

// ------- 128x64-tile NT GEMM (fp32 out): 512 blocks -> 2 blocks/CU for overlap -------
__global__ __launch_bounds__(256) void gemm_out(const bf16* __restrict__ A,
    const bf16* __restrict__ B, float* __restrict__ C)
{
    __shared__ __attribute__((aligned(16))) bf16 sA[128*32];
    __shared__ __attribute__((aligned(16))) bf16 sB[64*32];
    const int m0 = blockIdx.y * 128, n0 = blockIdx.x * 64;
    const int K = HIDDIM, ldc = HIDDIM;
    const int tid  = threadIdx.x;
    const int lane = tid & 63;
    const int w    = tid >> 6;           // wave 0..3
    const int wm   = w >> 1, wn = w & 1; // 2x2 waves of 64x32
    const int quad = lane >> 4, lr = lane & 15;
    const int srow = lane >> 2;          // staging: 16 rows x 4 lanes/row
    const int scol = (lane & 3) * 8;

    const bf16* gA0 = A + (size_t)(m0 + w*32 + srow) * K + scol;
    const bf16* gB0 = B + (size_t)(n0 + w*16 + srow) * K + scol;
    bf16* lA0 = &sA[w*1024];
    bf16* lB0 = &sB[w*512];

    v4f acc[4][2] = {};

    for (int kt = 0; kt < K; kt += 32) {
        __syncthreads();
        async16(lA0,       gA0 + kt);
        async16(lA0 + 512, gA0 + (size_t)16*K + kt);
        async16(lB0,       gB0 + kt);
        __syncthreads();
        v8bf a[4], b[2];
#pragma unroll
        for (int i = 0; i < 4; ++i)
            a[i] = *(const v8bf*)&sA[(wm*64 + i*16 + lr)*32 + quad*8];
#pragma unroll
        for (int j = 0; j < 2; ++j)
            b[j] = *(const v8bf*)&sB[(wn*32 + j*16 + lr)*32 + quad*8];
#pragma unroll
        for (int i = 0; i < 4; ++i)
#pragma unroll
            for (int j = 0; j < 2; ++j)
                acc[i][j] = __builtin_amdgcn_mfma_f32_16x16x32_bf16(a[i], b[j], acc[i][j], 0, 0, 0);
    }

#pragma unroll
    for (int i = 0; i < 4; ++i) {
        const int row_b = m0 + wm*64 + i*16 + quad*4;
#pragma unroll
        for (int j = 0; j < 2; ++j) {
            const int col = n0 + wn*32 + j*16 + lr;
#pragma unroll
            for (int r = 0; r < 4; ++r)
                C[(size_t)(row_b + r)*ldc + col] = acc[i][j][r];
        }
    }
}

// ---------------- ReBased feature map: y = LN(x*gamma+beta), q also * D^-0.5 ----------------
__global__ __launch_bounds__(256) void fmap(bf16* __restrict__ qb, bf16* __restrict__ kb,
                                            const float* __restrict__ gamma,
                                            const float* __restrict__ beta)
{
    const int rid  = blockIdx.x * 4 + (threadIdx.x >> 6);   // 0 .. 2*T*H-1
    const int lane = threadIdx.x & 63;
    bf16* base = (rid < TSEQ*NHEAD) ? (qb + (size_t)rid * HDIM)
                                    : (kb + (size_t)(rid - TSEQ*NHEAD) * HDIM);
    const float scale = (rid < TSEQ*NHEAD) ? 0.08838834764831845f : 1.0f; // D^-0.5 on q only

    const bf16 x0b = base[lane*2], x1b = base[lane*2+1];
    const float g0 = gamma[lane*2], g1 = gamma[lane*2+1];
    const float b0 = beta[lane*2],  b1 = beta[lane*2+1];
    float x0 = (float)x0b*g0 + b0;
    float x1 = (float)x1b*g1 + b1;
    float s  = x0 + x1;
    float sq = x0*x0 + x1*x1;
#pragma unroll
    for (int off = 1; off < 64; off <<= 1) { s += __shfl_xor(s, off); sq += __shfl_xor(sq, off); }
    const float mu   = s * (1.0f/128.0f);
    float var        = sq * (1.0f/128.0f) - mu*mu;
    var = fmaxf(var, 0.0f);
    const float rstd = rsqrtf(var + 1e-5f);
    base[lane*2]   = (bf16)((x0 - mu) * rstd * scale);
    base[lane*2+1] = (bf16)((x1 - mu) * rstd * scale);
}

// ---------------- 2048x2048 transpose (vt[c][t] = vb[t][c]) ----------------
__global__ __launch_bounds__(256) void transpose2048(const bf16* __restrict__ src,
                                                     bf16* __restrict__ dst)
{
    __shared__ __attribute__((aligned(16))) bf16 tile[64][72];
    const int t0 = blockIdx.y * 64, c0 = blockIdx.x * 64;
    const int tid = threadIdx.x;
    const int r = tid >> 3;            // 0..31
    const int c = (tid & 7) * 8;       // 0..56
#pragma unroll
    for (int p = 0; p < 2; ++p) {
        const int rr = r + p*32;
        *(v8bf*)&tile[rr][c] = *(const v8bf*)(src + (size_t)(t0+rr)*HIDDIM + c0 + c);
    }
    __syncthreads();
#pragma unroll
    for (int p = 0; p < 2; ++p) {
        const int orow = r + p*32;     // output row = original column
        v8bf o;
#pragma unroll
        for (int i = 0; i < 8; ++i) o[i] = tile[c + i][orow];
        *(v8bf*)(dst + (size_t)(c0+orow)*HIDDIM + t0 + c) = o;
    }
}

// ---------------- quadratic causal attention, paired 64-row q-tiles ----------------
// Balance fix: block handles tiles (31-p) and (p) -> exactly 33 chunks per block.
// grid = 16 pairs x 16 heads = 256 blocks (1/CU), 512 threads = 8 waves.
__global__ __launch_bounds__(512, 2) void attn(const bf16* __restrict__ qb,
                                               const bf16* __restrict__ kb,
                                               const bf16* __restrict__ vt,
                                               bf16* __restrict__ ob)
{
    __shared__ __attribute__((aligned(16))) bf16 sK[2*64*136];   // per-buf [s][d], pad 8
    __shared__ __attribute__((aligned(16))) bf16 sV[2*128*72];   // per-buf [d][s], pad 8
    __shared__ __attribute__((aligned(16))) bf16 sS[2*64*72];    // per-group [q][s], pad 8
    __shared__ __attribute__((aligned(16))) float sO[64*129];    // combine scratch, pad 1
    __shared__ __attribute__((aligned(16))) float sZ[64*17];

    const int h    = blockIdx.y;
    const int pr   = blockIdx.x;              // pair index 0..15
    const int tid  = threadIdx.x, lane = tid & 63;
    const int w    = tid >> 6;                // 0..7
    const int g    = w >> 2;                  // chunk group 0/1
    const int ww   = w & 3;                   // wave within group
    const int quad = lane >> 4, lr = lane & 15;
    const int rs   = tid >> 4;                // staging row 0..31 (x4 passes)
    const int cs   = (tid & 15) * 8;          // staging col 0..120

#pragma unroll
    for (int ti = 0; ti < 2; ++ti) {
        const int tile = ti ? pr : (31 - pr);
        const int nch  = tile + 1;

        // Q fragments (A-layout): wave owns q-rows [tile*64 + ww*16, +16)
        v8bf qa[4];
        {
            const bf16* q0 = qb + (size_t)(tile*64 + ww*16 + lr)*HIDDIM + h*HDIM + quad*8;
#pragma unroll
            for (int ks = 0; ks < 4; ++ks)
                qa[ks] = *(const v8bf*)(q0 + ks*32);
        }

        v4f  o[8] = {};
        float z[4] = {0.f, 0.f, 0.f, 0.f};

        v8bf curK[4], curV[4], nxtK[4], nxtV[4];
#pragma unroll
        for (int p = 0; p < 4; ++p) {
            curK[p] = *(const v8bf*)(kb + (size_t)(rs + p*32)*HIDDIM + h*HDIM + cs);
            curV[p] = *(const v8bf*)(vt + (size_t)(h*HDIM + rs + p*32)*HIDDIM + cs);
        }

        for (int ich = 0; ich < nch; ich += 2) {
            __syncthreads();                  // prev-iter LDS reads done
#pragma unroll
            for (int p = 0; p < 4; ++p) {
                const int r = rs + p*32;      // kv row within pair [0,128)
                *(v8bf*)&sK[(r>>6)*8704 + (r&63)*136 + cs] = curK[p];
            }
#pragma unroll
            for (int p = 0; p < 4; ++p)       // cs selects buffer (col>=64 -> buf 1)
                *(v8bf*)&sV[(cs>>6)*9216 + (rs + p*32)*72 + (cs & 63)] = curV[p];

            if (ich + 2 < nch) {              // prefetch next pair (overlaps compute)
                const int s1 = (ich + 2) * 64;
#pragma unroll
                for (int p = 0; p < 4; ++p) {
                    nxtK[p] = *(const v8bf*)(kb + (size_t)(s1 + rs + p*32)*HIDDIM + h*HDIM + cs);
                    nxtV[p] = *(const v8bf*)(vt + (size_t)(h*HDIM + rs + p*32)*HIDDIM + s1 + cs);
                }
            }
            __syncthreads();                  // tiles visible

            const int ch = ich + g;
            if (ch < nch) {
                const bf16* sKg = &sK[g*8704];
                const bf16* sVg = &sV[g*9216];
                bf16*       sSg = &sS[g*4608];
                const bool  diag = (ch == tile);
                const int   s0   = ch * 64;

                // QK^T -> square/mask -> z, sS (sS rows wave-private)
                v8bf kbf[4][4];
#pragma unroll
                for (int nj = 0; nj < 4; ++nj)
#pragma unroll
                    for (int ks = 0; ks < 4; ++ks)
                        kbf[nj][ks] = *(const v8bf*)&sKg[(nj*16 + lr)*136 + ks*32 + quad*8];
                const int row_l = ww*16 + quad*4;
                const int qg    = tile*64 + row_l;
#pragma unroll
                for (int nj = 0; nj < 4; ++nj) {
                    v4f s4 = {0.f, 0.f, 0.f, 0.f};
#pragma unroll
                    for (int ks = 0; ks < 4; ++ks)
                        s4 = __builtin_amdgcn_mfma_f32_16x16x32_bf16(qa[ks], kbf[nj][ks], s4, 0, 0, 0);
                    const int col = nj*16 + lr;
                    const int sg  = s0 + col;
#pragma unroll
                    for (int r = 0; r < 4; ++r) {
                        float val = s4[r] * s4[r];
                        if (diag && (sg > qg + r)) val = 0.0f;
                        const bf16 vb16 = (bf16)val;
                        z[r] += (float)vb16;           // consistent with what multiplies V
                        sSg[(row_l + r)*72 + col] = vb16;
                    }
                }

                // O += S * V
#pragma unroll
                for (int ks = 0; ks < 2; ++ks) {
                    const v8bf sa = *(const v8bf*)&sSg[(ww*16 + lr)*72 + ks*32 + quad*8];
#pragma unroll
                    for (int nd = 0; nd < 8; ++nd) {
                        const v8bf vbf = *(const v8bf*)&sVg[(nd*16 + lr)*72 + ks*32 + quad*8];
                        o[nd] = __builtin_amdgcn_mfma_f32_16x16x32_bf16(sa, vbf, o[nd], 0, 0, 0);
                    }
                }
            }

            if (ich + 2 < nch) {
#pragma unroll
                for (int p = 0; p < 4; ++p) { curK[p] = nxtK[p]; curV[p] = nxtV[p]; }
            }
        }

        // cross-group combine: group 1 dumps partial O,z; group 0 adds + epilogue.
        const int row_l = ww*16 + quad*4;
        __syncthreads();
        if (g == 1) {
#pragma unroll
            for (int nd = 0; nd < 8; ++nd)
#pragma unroll
                for (int r = 0; r < 4; ++r)
                    sO[(row_l + r)*129 + nd*16 + lr] = o[nd][r];
#pragma unroll
            for (int r = 0; r < 4; ++r)
                sZ[(row_l + r)*17 + lr] = z[r];
        }
        __syncthreads();
        if (g == 0) {
#pragma unroll
            for (int nd = 0; nd < 8; ++nd)
#pragma unroll
                for (int r = 0; r < 4; ++r)
                    o[nd][r] += sO[(row_l + r)*129 + nd*16 + lr];
#pragma unroll
            for (int r = 0; r < 4; ++r) {
                float zz = z[r] + sZ[(row_l + r)*17 + lr];
                zz += __shfl_xor(zz, 1); zz += __shfl_xor(zz, 2);
                zz += __shfl_xor(zz, 4); zz += __shfl_xor(zz, 8);
                z[r] = zz + 1e-5f;
            }
            const size_t rbase = (size_t)(tile*64 + row_l)*HIDDIM + h*HDIM;
#pragma unroll
            for (int nd = 0; nd < 8; ++nd) {
                const int col = nd*16 + lr;
#pragma unroll
                for (int r = 0; r < 4; ++r)
                    ob[rbase + (size_t)r*HIDDIM + col] = (bf16)(o[nd][r] / z[r]);
            }
        }
    }
}

extern "C" void kernel_launch(void* const* d_in, const int* in_sizes, int n_in,
                              void* d_out, int out_size, void* d_ws, size_t ws_size,
                              hipStream_t stream)
{
    const float* hs    = (const float*)d_in[0];
    const float* Wq    = (const float*)d_in[1];
    const float* Wk    = (const float*)d_in[2];
    const float* Wv    = (const float*)d_in[3];
    const float* Wo    = (const float*)d_in[4];
    const float* gamma = (const float*)d_in[5];
    const float* beta  = (const float*)d_in[6];
    float* outp = (float*)d_out;

    const size_t MAT = (size_t)TSEQ * HIDDIM;     // 4.19M elems

    // ws layout (6 bf16 slots of 8.39 MB): hs_b, Wcat(q,k,v contiguous!), Wo_b, vb.
    // qb/kb live in d_out (dead once gemm_out overwrites it with the final fp32
    // output). vt aliases hs_b (dead after gemm_qkv192); ob aliases vb (dead
    // after transpose).
    bf16* ws   = (bf16*)d_ws;
    bf16* hs_b = ws + 0*MAT;
    bf16* vt   = hs_b;
    bf16* Wq_b = ws + 1*MAT;                      // Wcat base
    bf16* Wk_b = ws + 2*MAT;
    bf16* Wv_b = ws + 3*MAT;
    bf16* Wo_b = ws + 4*MAT;
    bf16* vb   = ws + 5*MAT;
    bf16* ob   = vb;
    bf16* qb   = (bf16*)d_out;
    bf16* kb   = (bf16*)d_out + MAT;

    conv5<<<dim3(2048, 5), 256, 0, stream>>>(hs, hs_b, Wq, Wq_b, Wk, Wk_b, Wv, Wv_b, Wo, Wo_b);
    gemm_qkv192<<<dim3(32, 8), 512, 0, stream>>>(hs_b, Wq_b, qb, kb, vb);
    fmap<<<dim3(2*TSEQ*NHEAD/4), 256, 0, stream>>>(qb, kb, gamma, beta);
    transpose2048<<<dim3(32, 32), 256, 0, stream>>>(vb, vt);
    attn<<<dim3(16, 16), 512, 0, stream>>>(qb, kb, vt, ob);
    gemm_out<<<dim3(32, 16), 256, 0, stream>>>(ob, Wo_b, outp);
}

// Round 4
// 269.431 us; speedup vs baseline: 1.1117x; 1.0130x over previous
//
#include <hip/hip_runtime.h>
#include <hip/hip_bf16.h>
#include <stdint.h>

typedef __bf16 bf16;
typedef __bf16 v8bf __attribute__((ext_vector_type(8)));
typedef float  v4f  __attribute__((ext_vector_type(4)));

#define TSEQ   2048
#define HIDDIM 2048
#define NHEAD  16
#define HDIM   128

// async global->LDS, 16B per lane, LDS dest = wave-uniform base + lane*16 (m97 pattern)
__device__ __forceinline__ void async16(void* lds, const void* g)
{
    __builtin_amdgcn_global_load_lds(
        (__attribute__((address_space(1))) void*)(uintptr_t)g,
        (__attribute__((address_space(3))) void*)(unsigned int)(uintptr_t)lds,
        16, 0, 0);
}

// ---------------- f32 -> bf16 bulk convert: 5 matrices of TSEQ*HIDDIM ----------------
__global__ __launch_bounds__(256) void conv5(const float* __restrict__ s0, bf16* __restrict__ d0,
                                             const float* __restrict__ s1, bf16* __restrict__ d1,
                                             const float* __restrict__ s2, bf16* __restrict__ d2,
                                             const float* __restrict__ s3, bf16* __restrict__ d3,
                                             const float* __restrict__ s4, bf16* __restrict__ d4)
{
    const float* src; bf16* dst;
    switch (blockIdx.y) {
        case 0: src = s0; dst = d0; break;
        case 1: src = s1; dst = d1; break;
        case 2: src = s2; dst = d2; break;
        case 3: src = s3; dst = d3; break;
        default: src = s4; dst = d4; break;
    }
    const size_t i = ((size_t)blockIdx.x * 256 + threadIdx.x) * 8;
    const float4 a = *(const float4*)(src + i);
    const float4 b = *(const float4*)(src + i + 4);
    v8bf o;
    o[0] = (bf16)a.x; o[1] = (bf16)a.y; o[2] = (bf16)a.z; o[3] = (bf16)a.w;
    o[4] = (bf16)b.x; o[5] = (bf16)b.y; o[6] = (bf16)b.z; o[7] = (bf16)b.w;
    *(v8bf*)(dst + i) = o;
}

// ============ 128x384-tile 6-phase NT GEMM: C[2048,6144] = A * Wcat^T ============
// Grid 16x16 = 256 blocks = 1/CU. 512 thr = 8 waves (2M x 4N); per-wave 64 rows x
// {nh*128 + wn*32 + nj*16} cols (nh 0..2), acc[4][6]. BK=64, double-buffered 128 KiB
// LDS (A 2x16KB, B 2x48KB) via global_load_lds. Phase nh reads ONLY B-chunk nh
// (rows nh*128..+127) -> chunk freed right after its phase -> fully symmetric
// schedule: every staged unit lands 5 phases before its read. 16 MFMA/phase,
// counted vmcnt(10/12) at phase ends (never 0 in loop), <=16 loads in flight.
// Bank-deswizzle: 16B slot p of a 128B row holds logical slot p ^ (row&7), applied
// on the global SOURCE and on the LDS read address (both-sides rule).

#define PBAR() do { __builtin_amdgcn_sched_barrier(0); __builtin_amdgcn_s_barrier(); \
                    __builtin_amdgcn_sched_barrier(0); } while (0)

// stage one 128-row x 64-col unit (16 KB): 2 issues/thread, wave-uniform LDS base
#define STU(ldst, gsrc) do { \
    async16((ldst) + w*512,        (gsrc) + (size_t)(w*8 + (l>>3))*2048); \
    async16((ldst) + 4096 + w*512, (gsrc) + (size_t)(64 + w*8 + (l>>3))*2048); \
} while (0)

// A-frags of buffer buf -> a[0..3][0..1] (8 ds_read_b128)
#define RDA(buf) do { _Pragma("unroll") \
    for (int mi_ = 0; mi_ < 4; ++mi_) { \
        const bf16* p_ = &sA[(buf)*8192 + (wm*64 + mi_*16 + lr)*64]; \
        a[mi_][0] = *(const v8bf*)(p_ + c0); \
        a[mi_][1] = *(const v8bf*)(p_ + c1); } } while (0)

// B-frags for chunk nh of buffer buf -> b[0..1][0..1] (4 ds_read_b128)
#define RDB(buf, nh) do { _Pragma("unroll") \
    for (int nj_ = 0; nj_ < 2; ++nj_) { \
        const bf16* p_ = &sB[(buf)*24576 + ((nh)*128 + wn*32 + nj_*16 + lr)*64]; \
        b[nj_][0] = *(const v8bf*)(p_ + c0); \
        b[nj_][1] = *(const v8bf*)(p_ + c1); } } while (0)

// 16 MFMA: 4 mi x 2 nj x 2 k for column-group nh
#define MQ(nh) do { _Pragma("unroll") \
    for (int mi_ = 0; mi_ < 4; ++mi_) { _Pragma("unroll") \
        for (int nj_ = 0; nj_ < 2; ++nj_) { \
            acc[mi_][(nh)*2+nj_] = __builtin_amdgcn_mfma_f32_16x16x32_bf16( \
                a[mi_][0], b[nj_][0], acc[mi_][(nh)*2+nj_], 0, 0, 0); \
            acc[mi_][(nh)*2+nj_] = __builtin_amdgcn_mfma_f32_16x16x32_bf16( \
                a[mi_][1], b[nj_][1], acc[mi_][(nh)*2+nj_], 0, 0, 0); \
        } } } while (0)

#define VMC(n) asm volatile("s_waitcnt vmcnt(" #n ")" ::: "memory")

__global__ __launch_bounds__(512, 2) void gemm_qkv384(const bf16* __restrict__ A,
    const bf16* __restrict__ Wcat, bf16* __restrict__ qb, bf16* __restrict__ kb,
    bf16* __restrict__ vb)
{
    __shared__ __attribute__((aligned(16))) bf16 sA[2*8192];    // 2 x 128x64 = 32 KB
    __shared__ __attribute__((aligned(16))) bf16 sB[2*24576];   // 2 x 384x64 = 96 KB
    const int n0g = blockIdx.x * 384;         // over concat(Wq,Wk,Wv) rows (6144)
    const int m0  = blockIdx.y * 128;

    const int tid = threadIdx.x, l = tid & 63, w = tid >> 6;    // 8 waves
    const int wm = w >> 2, wn = w & 3;                          // 2x4 wave grid
    const int quad = l >> 4, lr = l & 15;
    const int scol = ((l & 7) ^ ((l >> 3) & 7)) * 8;            // staged source col
    const int c0 = ((quad    ) ^ (lr & 7)) * 8;                 // read deswizzle
    const int c1 = ((quad + 4) ^ (lr & 7)) * 8;

    const bf16* Ag = A    + (size_t)m0  * 2048 + scol;
    const bf16* Bg = Wcat + (size_t)n0g * 2048 + scol;

    v4f  acc[4][6] = {};
    v8bf a[4][2], b[2][2];

    // prologue (matches steady-state issue history): A(0) B0(0) B1(0) B2(0)
    // A(1) B0(1) B1(1) = 14 issues; B2(1) is staged at Ph0 of iter 0.
    STU(&sA[0],           Ag);
    STU(&sB[0],           Bg);
    STU(&sB[8192],        Bg + (size_t)128*2048);
    STU(&sB[16384],       Bg + (size_t)256*2048);
    STU(&sA[8192],        Ag + 64);
    STU(&sB[24576],       Bg + 64);
    STU(&sB[24576+8192],  Bg + (size_t)128*2048 + 64);
    VMC(10);                                   // A(0),B0(0) landed
    __builtin_amdgcn_s_barrier();
    __builtin_amdgcn_sched_barrier(0);

#pragma unroll 1
    for (int it = 0; it < 16; ++it) {          // tiles T=2it (buf0), T+1 (buf1)
        const int k1 =  it*128 + 64;                // tile T+1 (max 1984, no wrap)
        const int k2 = (it*128 + 128) & 2047;       // tile T+2 (wrap harmless last iter)
        const int k3 = (it*128 + 192) & 2047;       // tile T+3

        // Ph0: read A,B0(buf0); stage B2(T+1)->buf1 (read Ph5: 5-phase gap)
        RDA(0); RDB(0, 0);
        STU(&sB[24576+16384], Bg + (size_t)256*2048 + k1);
        PBAR(); __builtin_amdgcn_s_setprio(1); MQ(0); __builtin_amdgcn_s_setprio(0);
        VMC(10); PBAR();
        // Ph1: read B1(buf0); stage A,B0(T+2)->buf0 (read next Ph0/Ph0: 5)
        RDB(0, 1);
        STU(&sA[0], Ag + k2);
        STU(&sB[0], Bg + k2);
        PBAR(); __builtin_amdgcn_s_setprio(1); MQ(1); __builtin_amdgcn_s_setprio(0);
        VMC(12); PBAR();
        // Ph2: read B2(buf0); stage B1(T+2)->buf0 (read next Ph1: 5)
        RDB(0, 2);
        STU(&sB[8192], Bg + (size_t)128*2048 + k2);
        PBAR(); __builtin_amdgcn_s_setprio(1); MQ(2); __builtin_amdgcn_s_setprio(0);
        VMC(10); PBAR();
        // Ph3: read A,B0(buf1); stage B2(T+2)->buf0 (read next Ph2: 5)
        RDA(1); RDB(1, 0);
        STU(&sB[16384], Bg + (size_t)256*2048 + k2);
        PBAR(); __builtin_amdgcn_s_setprio(1); MQ(0); __builtin_amdgcn_s_setprio(0);
        VMC(10); PBAR();
        // Ph4: read B1(buf1); stage A,B0(T+3)->buf1 (read next Ph3: 5)
        RDB(1, 1);
        STU(&sA[8192],  Ag + k3);
        STU(&sB[24576], Bg + k3);
        PBAR(); __builtin_amdgcn_s_setprio(1); MQ(1); __builtin_amdgcn_s_setprio(0);
        VMC(12); PBAR();
        // Ph5: read B2(buf1); stage B1(T+3)->buf1 (read next Ph4: 5)
        RDB(1, 2);
        STU(&sB[24576+8192], Bg + (size_t)128*2048 + k3);
        PBAR(); __builtin_amdgcn_s_setprio(1); MQ(2); __builtin_amdgcn_s_setprio(0);
        VMC(10); PBAR();
    }
    asm volatile("s_waitcnt vmcnt(0)" ::: "memory");   // drain wrap refetches

    // epilogue: row = m0 + wm*64 + mi*16 + quad*4; col = n0g + nh*128 + wn*32 + nj*16 + lr
    // route to q/k/v by colg>>11 (16-col blocks never straddle a 2048 boundary)
#pragma unroll
    for (int mi = 0; mi < 4; ++mi) {
        const int row = m0 + wm*64 + mi*16 + quad*4;
#pragma unroll
        for (int j = 0; j < 6; ++j) {
            const int colg  = n0g + (j >> 1)*128 + wn*32 + (j & 1)*16;
            const int which = colg >> 11;
            bf16* Cb = (which == 0) ? qb : (which == 1) ? kb : vb;
            const int lcol = (colg & 2047) + lr;
#pragma unroll
            for (int r = 0; r < 4; ++r)
                Cb[(size_t)(row + r)*2048 + lcol] = (bf16)acc[mi][j][r];
        }
    }
}

// ------- 128x64-tile NT GEMM (fp32 out): 512 blocks -> 2 blocks/CU for overlap -------
__global__ __launch_bounds__(256) void gemm_out(const bf16* __restrict__ A,
    const bf16* __restrict__ B, float* __restrict__ C)
{
    __shared__ __attribute__((aligned(16))) bf16 sA[128*32];
    __shared__ __attribute__((aligned(16))) bf16 sB[64*32];
    const int m0 = blockIdx.y * 128, n0 = blockIdx.x * 64;
    const int K = HIDDIM, ldc = HIDDIM;
    const int tid  = threadIdx.x;
    const int lane = tid & 63;
    const int w    = tid >> 6;           // wave 0..3
    const int wm   = w >> 1, wn = w & 1; // 2x2 waves of 64x32
    const int quad = lane >> 4, lr = lane & 15;
    const int srow = lane >> 2;          // staging: 16 rows x 4 lanes/row
    const int scol = (lane & 3) * 8;

    const bf16* gA0 = A + (size_t)(m0 + w*32 + srow) * K + scol;
    const bf16* gB0 = B + (size_t)(n0 + w*16 + srow) * K + scol;
    bf16* lA0 = &sA[w*1024];
    bf16* lB0 = &sB[w*512];

    v4f acc[4][2] = {};

    for (int kt = 0; kt < K; kt += 32) {
        __syncthreads();
        async16(lA0,       gA0 + kt);
        async16(lA0 + 512, gA0 + (size_t)16*K + kt);
        async16(lB0,       gB0 + kt);
        __syncthreads();
        v8bf a[4], b[2];
#pragma unroll
        for (int i = 0; i < 4; ++i)
            a[i] = *(const v8bf*)&sA[(wm*64 + i*16 + lr)*32 + quad*8];
#pragma unroll
        for (int j = 0; j < 2; ++j)
            b[j] = *(const v8bf*)&sB[(wn*32 + j*16 + lr)*32 + quad*8];
#pragma unroll
        for (int i = 0; i < 4; ++i)
#pragma unroll
            for (int j = 0; j < 2; ++j)
                acc[i][j] = __builtin_amdgcn_mfma_f32_16x16x32_bf16(a[i], b[j], acc[i][j], 0, 0, 0);
    }

#pragma unroll
    for (int i = 0; i < 4; ++i) {
        const int row_b = m0 + wm*64 + i*16 + quad*4;
#pragma unroll
        for (int j = 0; j < 2; ++j) {
            const int col = n0 + wn*32 + j*16 + lr;
#pragma unroll
            for (int r = 0; r < 4; ++r)
                C[(size_t)(row_b + r)*ldc + col] = acc[i][j][r];
        }
    }
}

// ---------------- ReBased feature map: y = LN(x*gamma+beta), q also * D^-0.5 ----------------
__global__ __launch_bounds__(256) void fmap(bf16* __restrict__ qb, bf16* __restrict__ kb,
                                            const float* __restrict__ gamma,
                                            const float* __restrict__ beta)
{
    const int rid  = blockIdx.x * 4 + (threadIdx.x >> 6);   // 0 .. 2*T*H-1
    const int lane = threadIdx.x & 63;
    bf16* base = (rid < TSEQ*NHEAD) ? (qb + (size_t)rid * HDIM)
                                    : (kb + (size_t)(rid - TSEQ*NHEAD) * HDIM);
    const float scale = (rid < TSEQ*NHEAD) ? 0.08838834764831845f : 1.0f; // D^-0.5 on q only

    const bf16 x0b = base[lane*2], x1b = base[lane*2+1];
    const float g0 = gamma[lane*2], g1 = gamma[lane*2+1];
    const float b0 = beta[lane*2],  b1 = beta[lane*2+1];
    float x0 = (float)x0b*g0 + b0;
    float x1 = (float)x1b*g1 + b1;
    float s  = x0 + x1;
    float sq = x0*x0 + x1*x1;
#pragma unroll
    for (int off = 1; off < 64; off <<= 1) { s += __shfl_xor(s, off); sq += __shfl_xor(sq, off); }
    const float mu   = s * (1.0f/128.0f);
    float var        = sq * (1.0f/128.0f) - mu*mu;
    var = fmaxf(var, 0.0f);
    const float rstd = rsqrtf(var + 1e-5f);
    base[lane*2]   = (bf16)((x0 - mu) * rstd * scale);
    base[lane*2+1] = (bf16)((x1 - mu) * rstd * scale);
}

// ---------------- 2048x2048 transpose (vt[c][t] = vb[t][c]) ----------------
__global__ __launch_bounds__(256) void transpose2048(const bf16* __restrict__ src,
                                                     bf16* __restrict__ dst)
{
    __shared__ __attribute__((aligned(16))) bf16 tile[64][72];
    const int t0 = blockIdx.y * 64, c0 = blockIdx.x * 64;
    const int tid = threadIdx.x;
    const int r = tid >> 3;            // 0..31
    const int c = (tid & 7) * 8;       // 0..56
#pragma unroll
    for (int p = 0; p < 2; ++p) {
        const int rr = r + p*32;
        *(v8bf*)&tile[rr][c] = *(const v8bf*)(src + (size_t)(t0+rr)*HIDDIM + c0 + c);
    }
    __syncthreads();
#pragma unroll
    for (int p = 0; p < 2; ++p) {
        const int orow = r + p*32;     // output row = original column
        v8bf o;
#pragma unroll
        for (int i = 0; i < 8; ++i) o[i] = tile[c + i][orow];
        *(v8bf*)(dst + (size_t)(c0+orow)*HIDDIM + t0 + c) = o;
    }
}

// ---------------- quadratic causal attention, paired 64-row q-tiles ----------------
// Balance fix: block handles tiles (31-p) and (p) -> exactly 33 chunks per block.
// grid = 16 pairs x 16 heads = 256 blocks (1/CU), 512 threads = 8 waves.
__global__ __launch_bounds__(512, 2) void attn(const bf16* __restrict__ qb,
                                               const bf16* __restrict__ kb,
                                               const bf16* __restrict__ vt,
                                               bf16* __restrict__ ob)
{
    __shared__ __attribute__((aligned(16))) bf16 sK[2*64*136];   // per-buf [s][d], pad 8
    __shared__ __attribute__((aligned(16))) bf16 sV[2*128*72];   // per-buf [d][s], pad 8
    __shared__ __attribute__((aligned(16))) bf16 sS[2*64*72];    // per-group [q][s], pad 8
    __shared__ __attribute__((aligned(16))) float sO[64*129];    // combine scratch, pad 1
    __shared__ __attribute__((aligned(16))) float sZ[64*17];

    const int h    = blockIdx.y;
    const int pr   = blockIdx.x;              // pair index 0..15
    const int tid  = threadIdx.x, lane = tid & 63;
    const int w    = tid >> 6;                // 0..7
    const int g    = w >> 2;                  // chunk group 0/1
    const int ww   = w & 3;                   // wave within group
    const int quad = lane >> 4, lr = lane & 15;
    const int rs   = tid >> 4;                // staging row 0..31 (x4 passes)
    const int cs   = (tid & 15) * 8;          // staging col 0..120

#pragma unroll
    for (int ti = 0; ti < 2; ++ti) {
        const int tile = ti ? pr : (31 - pr);
        const int nch  = tile + 1;

        // Q fragments (A-layout): wave owns q-rows [tile*64 + ww*16, +16)
        v8bf qa[4];
        {
            const bf16* q0 = qb + (size_t)(tile*64 + ww*16 + lr)*HIDDIM + h*HDIM + quad*8;
#pragma unroll
            for (int ks = 0; ks < 4; ++ks)
                qa[ks] = *(const v8bf*)(q0 + ks*32);
        }

        v4f  o[8] = {};
        float z[4] = {0.f, 0.f, 0.f, 0.f};

        v8bf curK[4], curV[4], nxtK[4], nxtV[4];
#pragma unroll
        for (int p = 0; p < 4; ++p) {
            curK[p] = *(const v8bf*)(kb + (size_t)(rs + p*32)*HIDDIM + h*HDIM + cs);
            curV[p] = *(const v8bf*)(vt + (size_t)(h*HDIM + rs + p*32)*HIDDIM + cs);
        }

        for (int ich = 0; ich < nch; ich += 2) {
            __syncthreads();                  // prev-chunk LDS reads done
#pragma unroll
            for (int p = 0; p < 4; ++p) {
                const int r = rs + p*32;      // kv row within pair [0,128)
                *(v8bf*)&sK[(r>>6)*8704 + (r&63)*136 + cs] = curK[p];
            }
#pragma unroll
            for (int p = 0; p < 4; ++p)       // cs selects buffer (col>=64 -> buf 1)
                *(v8bf*)&sV[(cs>>6)*9216 + (rs + p*32)*72 + (cs & 63)] = curV[p];

            if (ich + 2 < nch) {              // prefetch next pair (overlaps compute)
                const int s1 = (ich + 2) * 64;
#pragma unroll
                for (int p = 0; p < 4; ++p) {
                    nxtK[p] = *(const v8bf*)(kb + (size_t)(s1 + rs + p*32)*HIDDIM + h*HDIM + cs);
                    nxtV[p] = *(const v8bf*)(vt + (size_t)(h*HDIM + rs + p*32)*HIDDIM + s1 + cs);
                }
            }
            __syncthreads();                  // tiles visible

            const int ch = ich + g;
            if (ch < nch) {
                const bf16* sKg = &sK[g*8704];
                const bf16* sVg = &sV[g*9216];
                bf16*       sSg = &sS[g*4608];
                const bool  diag = (ch == tile);
                const int   s0   = ch * 64;

                // QK^T -> square/mask -> z, sS (sS rows wave-private)
                v8bf kbf[4][4];
#pragma unroll
                for (int nj = 0; nj < 4; ++nj)
#pragma unroll
                    for (int ks = 0; ks < 4; ++ks)
                        kbf[nj][ks] = *(const v8bf*)&sKg[(nj*16 + lr)*136 + ks*32 + quad*8];
                const int row_l = ww*16 + quad*4;
                const int qg    = tile*64 + row_l;
#pragma unroll
                for (int nj = 0; nj < 4; ++nj) {
                    v4f s4 = {0.f, 0.f, 0.f, 0.f};
#pragma unroll
                    for (int ks = 0; ks < 4; ++ks)
                        s4 = __builtin_amdgcn_mfma_f32_16x16x32_bf16(qa[ks], kbf[nj][ks], s4, 0, 0, 0);
                    const int col = nj*16 + lr;
                    const int sg  = s0 + col;
#pragma unroll
                    for (int r = 0; r < 4; ++r) {
                        float val = s4[r] * s4[r];
                        if (diag && (sg > qg + r)) val = 0.0f;
                        const bf16 vb16 = (bf16)val;
                        z[r] += (float)vb16;           // consistent with what multiplies V
                        sSg[(row_l + r)*72 + col] = vb16;
                    }
                }

                // O += S * V
#pragma unroll
                for (int ks = 0; ks < 2; ++ks) {
                    const v8bf sa = *(const v8bf*)&sSg[(ww*16 + lr)*72 + ks*32 + quad*8];
#pragma unroll
                    for (int nd = 0; nd < 8; ++nd) {
                        const v8bf vbf = *(const v8bf*)&sVg[(nd*16 + lr)*72 + ks*32 + quad*8];
                        o[nd] = __builtin_amdgcn_mfma_f32_16x16x32_bf16(sa, vbf, o[nd], 0, 0, 0);
                    }
                }
            }

            if (ich + 2 < nch) {
#pragma unroll
                for (int p = 0; p < 4; ++p) { curK[p] = nxtK[p]; curV[p] = nxtV[p]; }
            }
        }

        // cross-group combine: group 1 dumps partial O,z; group 0 adds + epilogue.
        const int row_l = ww*16 + quad*4;
        __syncthreads();
        if (g == 1) {
#pragma unroll
            for (int nd = 0; nd < 8; ++nd)
#pragma unroll
                for (int r = 0; r < 4; ++r)
                    sO[(row_l + r)*129 + nd*16 + lr] = o[nd][r];
#pragma unroll
            for (int r = 0; r < 4; ++r)
                sZ[(row_l + r)*17 + lr] = z[r];
        }
        __syncthreads();
        if (g == 0) {
#pragma unroll
            for (int nd = 0; nd < 8; ++nd)
#pragma unroll
                for (int r = 0; r < 4; ++r)
                    o[nd][r] += sO[(row_l + r)*129 + nd*16 + lr];
#pragma unroll
            for (int r = 0; r < 4; ++r) {
                float zz = z[r] + sZ[(row_l + r)*17 + lr];
                zz += __shfl_xor(zz, 1); zz += __shfl_xor(zz, 2);
                zz += __shfl_xor(zz, 4); zz += __shfl_xor(zz, 8);
                z[r] = zz + 1e-5f;
            }
            const size_t rbase = (size_t)(tile*64 + row_l)*HIDDIM + h*HDIM;
#pragma unroll
            for (int nd = 0; nd < 8; ++nd) {
                const int col = nd*16 + lr;
#pragma unroll
                for (int r = 0; r < 4; ++r)
                    ob[rbase + (size_t)r*HIDDIM + col] = (bf16)(o[nd][r] / z[r]);
            }
        }
    }
}

extern "C" void kernel_launch(void* const* d_in, const int* in_sizes, int n_in,
                              void* d_out, int out_size, void* d_ws, size_t ws_size,
                              hipStream_t stream)
{
    const float* hs    = (const float*)d_in[0];
    const float* Wq    = (const float*)d_in[1];
    const float* Wk    = (const float*)d_in[2];
    const float* Wv    = (const float*)d_in[3];
    const float* Wo    = (const float*)d_in[4];
    const float* gamma = (const float*)d_in[5];
    const float* beta  = (const float*)d_in[6];
    float* outp = (float*)d_out;

    const size_t MAT = (size_t)TSEQ * HIDDIM;     // 4.19M elems

    // ws layout (6 bf16 slots of 8.39 MB): hs_b, Wcat(q,k,v contiguous!), Wo_b, vb.
    // qb/kb live in d_out (dead once gemm_out overwrites it with the final fp32
    // output). vt aliases hs_b (dead after gemm_qkv384); ob aliases vb (dead
    // after transpose).
    bf16* ws   = (bf16*)d_ws;
    bf16* hs_b = ws + 0*MAT;
    bf16* vt   = hs_b;
    bf16* Wq_b = ws + 1*MAT;                      // Wcat base
    bf16* Wk_b = ws + 2*MAT;
    bf16* Wv_b = ws + 3*MAT;
    bf16* Wo_b = ws + 4*MAT;
    bf16* vb   = ws + 5*MAT;
    bf16* ob   = vb;
    bf16* qb   = (bf16*)d_out;
    bf16* kb   = (bf16*)d_out + MAT;

    conv5<<<dim3(2048, 5), 256, 0, stream>>>(hs, hs_b, Wq, Wq_b, Wk, Wk_b, Wv, Wv_b, Wo, Wo_b);
    gemm_qkv384<<<dim3(16, 16), 512, 0, stream>>>(hs_b, Wq_b, qb, kb, vb);
    fmap<<<dim3(2*TSEQ*NHEAD/4), 256, 0, stream>>>(qb, kb, gamma, beta);
    transpose2048<<<dim3(32, 32), 256, 0, stream>>>(vb, vt);
    attn<<<dim3(16, 16), 512, 0, stream>>>(qb, kb, vt, ob);
    gemm_out<<<dim3(32, 16), 256, 0, stream>>>(ob, Wo_b, outp);
}

// Round 5
// 266.755 us; speedup vs baseline: 1.1229x; 1.0100x over previous
//
#include <hip/hip_runtime.h>
#include <hip/hip_bf16.h>
#include <stdint.h>

typedef __bf16 bf16;
typedef __bf16 v8bf __attribute__((ext_vector_type(8)));
typedef __bf16 v4bf __attribute__((ext_vector_type(4)));
typedef float  v4f  __attribute__((ext_vector_type(4)));

#define TSEQ   2048
#define HIDDIM 2048
#define NHEAD  16
#define HDIM   128

// async global->LDS, 16B per lane, LDS dest = wave-uniform base + lane*16 (m97 pattern)
__device__ __forceinline__ void async16(void* lds, const void* g)
{
    __builtin_amdgcn_global_load_lds(
        (__attribute__((address_space(1))) void*)(uintptr_t)g,
        (__attribute__((address_space(3))) void*)(unsigned int)(uintptr_t)lds,
        16, 0, 0);
}

// ---------------- f32 -> bf16 bulk convert: 5 matrices of TSEQ*HIDDIM ----------------
__global__ __launch_bounds__(256) void conv5(const float* __restrict__ s0, bf16* __restrict__ d0,
                                             const float* __restrict__ s1, bf16* __restrict__ d1,
                                             const float* __restrict__ s2, bf16* __restrict__ d2,
                                             const float* __restrict__ s3, bf16* __restrict__ d3,
                                             const float* __restrict__ s4, bf16* __restrict__ d4)
{
    const float* src; bf16* dst;
    switch (blockIdx.y) {
        case 0: src = s0; dst = d0; break;
        case 1: src = s1; dst = d1; break;
        case 2: src = s2; dst = d2; break;
        case 3: src = s3; dst = d3; break;
        default: src = s4; dst = d4; break;
    }
    const size_t i = ((size_t)blockIdx.x * 256 + threadIdx.x) * 8;
    const float4 a = *(const float4*)(src + i);
    const float4 b = *(const float4*)(src + i + 4);
    v8bf o;
    o[0] = (bf16)a.x; o[1] = (bf16)a.y; o[2] = (bf16)a.z; o[3] = (bf16)a.w;
    o[4] = (bf16)b.x; o[5] = (bf16)b.y; o[6] = (bf16)b.z; o[7] = (bf16)b.w;
    *(v8bf*)(dst + i) = o;
}

// ============ 128x384-tile 6-phase NT GEMM + fused ReBased fmap + fused V-transpose ===========
// C[2048,6144] = A * Wcat^T. Grid 16x16 = 256 blocks = 1/CU. 512 thr = 8 waves (2M x 4N);
// per-wave 64 rows x {nh*128 + wn*32 + nj*16} cols (nh 0..2), acc[4][6]. BK=64, double-
// buffered 128 KiB LDS via global_load_lds. 16 MFMA/phase, counted vmcnt (never 0 in loop).
// Bank-deswizzle both-sides: slot p of a 128B row holds logical slot p ^ (row&7).
// EPILOGUE FUSION: each block's 384 cols = exactly 3 full heads. q/k heads: LayerNorm
// (x*gamma+beta) per row over the 128-col head (shfl over 16-lane frag dim + cross-wave
// LDS combine in the dead sA buffer), q also * D^-0.5. V heads: store transposed
// directly into vt[c][t] (lane holds 4 consecutive t -> 8B stores).

#define PBAR() do { __builtin_amdgcn_sched_barrier(0); __builtin_amdgcn_s_barrier(); \
                    __builtin_amdgcn_sched_barrier(0); } while (0)

// stage one 128-row x 64-col unit (16 KB): 2 issues/thread, wave-uniform LDS base
#define STU(ldst, gsrc) do { \
    async16((ldst) + w*512,        (gsrc) + (size_t)(w*8 + (l>>3))*2048); \
    async16((ldst) + 4096 + w*512, (gsrc) + (size_t)(64 + w*8 + (l>>3))*2048); \
} while (0)

// A-frags of buffer buf -> a[0..3][0..1] (8 ds_read_b128)
#define RDA(buf) do { _Pragma("unroll") \
    for (int mi_ = 0; mi_ < 4; ++mi_) { \
        const bf16* p_ = &sA[(buf)*8192 + (wm*64 + mi_*16 + lr)*64]; \
        a[mi_][0] = *(const v8bf*)(p_ + c0); \
        a[mi_][1] = *(const v8bf*)(p_ + c1); } } while (0)

// B-frags for chunk nh of buffer buf -> b[0..1][0..1] (4 ds_read_b128)
#define RDB(buf, nh) do { _Pragma("unroll") \
    for (int nj_ = 0; nj_ < 2; ++nj_) { \
        const bf16* p_ = &sB[(buf)*24576 + ((nh)*128 + wn*32 + nj_*16 + lr)*64]; \
        b[nj_][0] = *(const v8bf*)(p_ + c0); \
        b[nj_][1] = *(const v8bf*)(p_ + c1); } } while (0)

// 16 MFMA: 4 mi x 2 nj x 2 k for column-group nh
#define MQ(nh) do { _Pragma("unroll") \
    for (int mi_ = 0; mi_ < 4; ++mi_) { _Pragma("unroll") \
        for (int nj_ = 0; nj_ < 2; ++nj_) { \
            acc[mi_][(nh)*2+nj_] = __builtin_amdgcn_mfma_f32_16x16x32_bf16( \
                a[mi_][0], b[nj_][0], acc[mi_][(nh)*2+nj_], 0, 0, 0); \
            acc[mi_][(nh)*2+nj_] = __builtin_amdgcn_mfma_f32_16x16x32_bf16( \
                a[mi_][1], b[nj_][1], acc[mi_][(nh)*2+nj_], 0, 0, 0); \
        } } } while (0)

#define VMC(n) asm volatile("s_waitcnt vmcnt(" #n ")" ::: "memory")

__global__ __launch_bounds__(512, 2) void gemm_qkv384(const bf16* __restrict__ A,
    const bf16* __restrict__ Wcat, bf16* __restrict__ qb, bf16* __restrict__ kb,
    bf16* __restrict__ vt, const float* __restrict__ gamma, const float* __restrict__ beta)
{
    __shared__ __attribute__((aligned(16))) bf16 sA[2*8192];    // 2 x 128x64 = 32 KB
    __shared__ __attribute__((aligned(16))) bf16 sB[2*24576];   // 2 x 384x64 = 96 KB
    const int n0g = blockIdx.x * 384;         // over concat(Wq,Wk,Wv) rows (6144)
    const int m0  = blockIdx.y * 128;

    const int tid = threadIdx.x, l = tid & 63, w = tid >> 6;    // 8 waves
    const int wm = w >> 2, wn = w & 3;                          // 2x4 wave grid
    const int quad = l >> 4, lr = l & 15;
    const int scol = ((l & 7) ^ ((l >> 3) & 7)) * 8;            // staged source col
    const int c0 = ((quad    ) ^ (lr & 7)) * 8;                 // read deswizzle
    const int c1 = ((quad + 4) ^ (lr & 7)) * 8;

    const bf16* Ag = A    + (size_t)m0  * 2048 + scol;
    const bf16* Bg = Wcat + (size_t)n0g * 2048 + scol;

    v4f  acc[4][6] = {};
    v8bf a[4][2], b[2][2];

    // prologue (matches steady-state issue history): A(0) B0(0) B1(0) B2(0)
    // A(1) B0(1) B1(1) = 14 issues; B2(1) is staged at Ph0 of iter 0.
    STU(&sA[0],           Ag);
    STU(&sB[0],           Bg);
    STU(&sB[8192],        Bg + (size_t)128*2048);
    STU(&sB[16384],       Bg + (size_t)256*2048);
    STU(&sA[8192],        Ag + 64);
    STU(&sB[24576],       Bg + 64);
    STU(&sB[24576+8192],  Bg + (size_t)128*2048 + 64);
    VMC(10);                                   // A(0),B0(0) landed
    __builtin_amdgcn_s_barrier();
    __builtin_amdgcn_sched_barrier(0);

#pragma unroll 1
    for (int it = 0; it < 16; ++it) {          // tiles T=2it (buf0), T+1 (buf1)
        const int k1 =  it*128 + 64;                // tile T+1 (max 1984, no wrap)
        const int k2 = (it*128 + 128) & 2047;       // tile T+2 (wrap harmless last iter)
        const int k3 = (it*128 + 192) & 2047;       // tile T+3

        // Ph0: read A,B0(buf0); stage B2(T+1)->buf1 (read Ph5: 5-phase gap)
        RDA(0); RDB(0, 0);
        STU(&sB[24576+16384], Bg + (size_t)256*2048 + k1);
        PBAR(); __builtin_amdgcn_s_setprio(1); MQ(0); __builtin_amdgcn_s_setprio(0);
        VMC(10); PBAR();
        // Ph1: read B1(buf0); stage A,B0(T+2)->buf0 (read next Ph0: 5)
        RDB(0, 1);
        STU(&sA[0], Ag + k2);
        STU(&sB[0], Bg + k2);
        PBAR(); __builtin_amdgcn_s_setprio(1); MQ(1); __builtin_amdgcn_s_setprio(0);
        VMC(12); PBAR();
        // Ph2: read B2(buf0); stage B1(T+2)->buf0 (read next Ph1: 5)
        RDB(0, 2);
        STU(&sB[8192], Bg + (size_t)128*2048 + k2);
        PBAR(); __builtin_amdgcn_s_setprio(1); MQ(2); __builtin_amdgcn_s_setprio(0);
        VMC(10); PBAR();
        // Ph3: read A,B0(buf1); stage B2(T+2)->buf0 (read next Ph2: 5)
        RDA(1); RDB(1, 0);
        STU(&sB[16384], Bg + (size_t)256*2048 + k2);
        PBAR(); __builtin_amdgcn_s_setprio(1); MQ(0); __builtin_amdgcn_s_setprio(0);
        VMC(10); PBAR();
        // Ph4: read B1(buf1); stage A,B0(T+3)->buf1 (read next Ph3: 5)
        RDB(1, 1);
        STU(&sA[8192],  Ag + k3);
        STU(&sB[24576], Bg + k3);
        PBAR(); __builtin_amdgcn_s_setprio(1); MQ(1); __builtin_amdgcn_s_setprio(0);
        VMC(12); PBAR();
        // Ph5: read B2(buf1); stage B1(T+3)->buf1 (read next Ph4: 5)
        RDB(1, 2);
        STU(&sB[24576+8192], Bg + (size_t)128*2048 + k3);
        PBAR(); __builtin_amdgcn_s_setprio(1); MQ(2); __builtin_amdgcn_s_setprio(0);
        VMC(10); PBAR();
    }
    asm volatile("s_waitcnt vmcnt(0)" ::: "memory");   // drain wrap refetches
    __syncthreads();                                   // all waves' stages landed -> sA dead

    // ---------------- fused feature map: LN over each 128-col head (q/k only) -------------
    // sRed[nh][row][wn] = (sum, sumsq); float2 units, row stride 5 float2 (bank-spread)
    float* sRed = (float*)sA;                          // 3*128*5*2 f32 = 15.4 KB < 32 KB
    const float g0f = gamma[wn*32 + lr],      b0f = beta[wn*32 + lr];
    const float g1f = gamma[wn*32 + 16 + lr], b1f = beta[wn*32 + 16 + lr];

#pragma unroll
    for (int nh = 0; nh < 3; ++nh) {
        if (((n0g + nh*128) >> 11) == 2) continue;     // V head: no feature map
#pragma unroll
        for (int mi = 0; mi < 4; ++mi) {
            float s[4] = {0.f,0.f,0.f,0.f}, sq[4] = {0.f,0.f,0.f,0.f};
#pragma unroll
            for (int jj = 0; jj < 2; ++jj) {
                const float gg = jj ? g1f : g0f, bb = jj ? b1f : b0f;
#pragma unroll
                for (int r = 0; r < 4; ++r) {
                    float x = acc[mi][nh*2+jj][r] * gg + bb;
                    acc[mi][nh*2+jj][r] = x;
                    s[r] += x; sq[r] += x*x;
                }
            }
#pragma unroll
            for (int off = 1; off < 16; off <<= 1)
#pragma unroll
                for (int r = 0; r < 4; ++r) {
                    s[r]  += __shfl_xor(s[r],  off);
                    sq[r] += __shfl_xor(sq[r], off);
                }
            if (lr == 0) {
#pragma unroll
                for (int r = 0; r < 4; ++r) {
                    const int row = wm*64 + mi*16 + quad*4 + r;
                    float* p = &sRed[((nh*128 + row)*5 + wn)*2];
                    p[0] = s[r]; p[1] = sq[r];
                }
            }
        }
    }
    __syncthreads();

    // ---------------- epilogue: normalize + store (q/k) or transposed store (V) ----------
#pragma unroll
    for (int mi = 0; mi < 4; ++mi) {
        const int row = m0 + wm*64 + mi*16 + quad*4;   // global t of r=0
        const int rl0 = wm*64 + mi*16 + quad*4;        // row within block
#pragma unroll
        for (int nh = 0; nh < 3; ++nh) {
            const int colg  = n0g + nh*128 + wn*32;
            const int which = colg >> 11;
            if (which == 2) {
                // V: vt[c][t], c = head feature, t contiguous per lane -> 8B stores
#pragma unroll
                for (int jj = 0; jj < 2; ++jj) {
                    const int c = (colg & 2047) + jj*16 + lr;
                    v4bf pk;
#pragma unroll
                    for (int r = 0; r < 4; ++r) pk[r] = (bf16)acc[mi][nh*2+jj][r];
                    *(v4bf*)(vt + (size_t)c*2048 + row) = pk;
                }
            } else {
                bf16* Cb = (which == 0) ? qb : kb;
                const float qs = (which == 0) ? 0.08838834764831845f : 1.0f; // D^-0.5 on q
#pragma unroll
                for (int r = 0; r < 4; ++r) {
                    const int rl = rl0 + r;
                    float S = 0.f, Q = 0.f;
#pragma unroll
                    for (int t = 0; t < 4; ++t) {
                        const float* p = &sRed[((nh*128 + rl)*5 + t)*2];
                        S += p[0]; Q += p[1];
                    }
                    const float mu = S * (1.0f/128.0f);
                    float var = Q * (1.0f/128.0f) - mu*mu;
                    var = fmaxf(var, 0.0f);
                    const float rstd = rsqrtf(var + 1e-5f) * qs;
#pragma unroll
                    for (int jj = 0; jj < 2; ++jj) {
                        const int lcol = (colg & 2047) + jj*16 + lr;
                        Cb[(size_t)(row + r)*2048 + lcol] =
                            (bf16)((acc[mi][nh*2+jj][r] - mu) * rstd);
                    }
                }
            }
        }
    }
}

// ------- 128x64-tile NT GEMM (fp32 out): 512 blocks -> 2 blocks/CU for overlap -------
__global__ __launch_bounds__(256) void gemm_out(const bf16* __restrict__ A,
    const bf16* __restrict__ B, float* __restrict__ C)
{
    __shared__ __attribute__((aligned(16))) bf16 sA[128*32];
    __shared__ __attribute__((aligned(16))) bf16 sB[64*32];
    const int m0 = blockIdx.y * 128, n0 = blockIdx.x * 64;
    const int K = HIDDIM, ldc = HIDDIM;
    const int tid  = threadIdx.x;
    const int lane = tid & 63;
    const int w    = tid >> 6;           // wave 0..3
    const int wm   = w >> 1, wn = w & 1; // 2x2 waves of 64x32
    const int quad = lane >> 4, lr = lane & 15;
    const int srow = lane >> 2;          // staging: 16 rows x 4 lanes/row
    const int scol = (lane & 3) * 8;

    const bf16* gA0 = A + (size_t)(m0 + w*32 + srow) * K + scol;
    const bf16* gB0 = B + (size_t)(n0 + w*16 + srow) * K + scol;
    bf16* lA0 = &sA[w*1024];
    bf16* lB0 = &sB[w*512];

    v4f acc[4][2] = {};

    for (int kt = 0; kt < K; kt += 32) {
        __syncthreads();
        async16(lA0,       gA0 + kt);
        async16(lA0 + 512, gA0 + (size_t)16*K + kt);
        async16(lB0,       gB0 + kt);
        __syncthreads();
        v8bf a[4], b[2];
#pragma unroll
        for (int i = 0; i < 4; ++i)
            a[i] = *(const v8bf*)&sA[(wm*64 + i*16 + lr)*32 + quad*8];
#pragma unroll
        for (int j = 0; j < 2; ++j)
            b[j] = *(const v8bf*)&sB[(wn*32 + j*16 + lr)*32 + quad*8];
#pragma unroll
        for (int i = 0; i < 4; ++i)
#pragma unroll
            for (int j = 0; j < 2; ++j)
                acc[i][j] = __builtin_amdgcn_mfma_f32_16x16x32_bf16(a[i], b[j], acc[i][j], 0, 0, 0);
    }

#pragma unroll
    for (int i = 0; i < 4; ++i) {
        const int row_b = m0 + wm*64 + i*16 + quad*4;
#pragma unroll
        for (int j = 0; j < 2; ++j) {
            const int col = n0 + wn*32 + j*16 + lr;
#pragma unroll
            for (int r = 0; r < 4; ++r)
                C[(size_t)(row_b + r)*ldc + col] = acc[i][j][r];
        }
    }
}

// ---------------- quadratic causal attention, paired 64-row q-tiles ----------------
// Balance fix: block handles tiles (31-p) and (p) -> exactly 33 chunks per block.
// grid = 16 pairs x 16 heads = 256 blocks (1/CU), 512 threads = 8 waves.
__global__ __launch_bounds__(512, 2) void attn(const bf16* __restrict__ qb,
                                               const bf16* __restrict__ kb,
                                               const bf16* __restrict__ vt,
                                               bf16* __restrict__ ob)
{
    __shared__ __attribute__((aligned(16))) bf16 sK[2*64*136];   // per-buf [s][d], pad 8
    __shared__ __attribute__((aligned(16))) bf16 sV[2*128*72];   // per-buf [d][s], pad 8
    __shared__ __attribute__((aligned(16))) bf16 sS[2*64*72];    // per-group [q][s], pad 8
    __shared__ __attribute__((aligned(16))) float sO[64*129];    // combine scratch, pad 1
    __shared__ __attribute__((aligned(16))) float sZ[64*17];

    const int h    = blockIdx.y;
    const int pr   = blockIdx.x;              // pair index 0..15
    const int tid  = threadIdx.x, lane = tid & 63;
    const int w    = tid >> 6;                // 0..7
    const int g    = w >> 2;                  // chunk group 0/1
    const int ww   = w & 3;                   // wave within group
    const int quad = lane >> 4, lr = lane & 15;
    const int rs   = tid >> 4;                // staging row 0..31 (x4 passes)
    const int cs   = (tid & 15) * 8;          // staging col 0..120

#pragma unroll
    for (int ti = 0; ti < 2; ++ti) {
        const int tile = ti ? pr : (31 - pr);
        const int nch  = tile + 1;

        // Q fragments (A-layout): wave owns q-rows [tile*64 + ww*16, +16)
        v8bf qa[4];
        {
            const bf16* q0 = qb + (size_t)(tile*64 + ww*16 + lr)*HIDDIM + h*HDIM + quad*8;
#pragma unroll
            for (int ks = 0; ks < 4; ++ks)
                qa[ks] = *(const v8bf*)(q0 + ks*32);
        }

        v4f  o[8] = {};
        float z[4] = {0.f, 0.f, 0.f, 0.f};

        v8bf curK[4], curV[4], nxtK[4], nxtV[4];
#pragma unroll
        for (int p = 0; p < 4; ++p) {
            curK[p] = *(const v8bf*)(kb + (size_t)(rs + p*32)*HIDDIM + h*HDIM + cs);
            curV[p] = *(const v8bf*)(vt + (size_t)(h*HDIM + rs + p*32)*HIDDIM + cs);
        }

        for (int ich = 0; ich < nch; ich += 2) {
            __syncthreads();                  // prev-chunk LDS reads done
#pragma unroll
            for (int p = 0; p < 4; ++p) {
                const int r = rs + p*32;      // kv row within pair [0,128)
                *(v8bf*)&sK[(r>>6)*8704 + (r&63)*136 + cs] = curK[p];
            }
#pragma unroll
            for (int p = 0; p < 4; ++p)       // cs selects buffer (col>=64 -> buf 1)
                *(v8bf*)&sV[(cs>>6)*9216 + (rs + p*32)*72 + (cs & 63)] = curV[p];

            if (ich + 2 < nch) {              // prefetch next pair (overlaps compute)
                const int s1 = (ich + 2) * 64;
#pragma unroll
                for (int p = 0; p < 4; ++p) {
                    nxtK[p] = *(const v8bf*)(kb + (size_t)(s1 + rs + p*32)*HIDDIM + h*HDIM + cs);
                    nxtV[p] = *(const v8bf*)(vt + (size_t)(h*HDIM + rs + p*32)*HIDDIM + s1 + cs);
                }
            }
            __syncthreads();                  // tiles visible

            const int ch = ich + g;
            if (ch < nch) {
                const bf16* sKg = &sK[g*8704];
                const bf16* sVg = &sV[g*9216];
                bf16*       sSg = &sS[g*4608];
                const bool  diag = (ch == tile);
                const int   s0   = ch * 64;

                // QK^T -> square/mask -> z, sS (sS rows wave-private)
                v8bf kbf[4][4];
#pragma unroll
                for (int nj = 0; nj < 4; ++nj)
#pragma unroll
                    for (int ks = 0; ks < 4; ++ks)
                        kbf[nj][ks] = *(const v8bf*)&sKg[(nj*16 + lr)*136 + ks*32 + quad*8];
                const int row_l = ww*16 + quad*4;
                const int qg    = tile*64 + row_l;
#pragma unroll
                for (int nj = 0; nj < 4; ++nj) {
                    v4f s4 = {0.f, 0.f, 0.f, 0.f};
#pragma unroll
                    for (int ks = 0; ks < 4; ++ks)
                        s4 = __builtin_amdgcn_mfma_f32_16x16x32_bf16(qa[ks], kbf[nj][ks], s4, 0, 0, 0);
                    const int col = nj*16 + lr;
                    const int sg  = s0 + col;
#pragma unroll
                    for (int r = 0; r < 4; ++r) {
                        float val = s4[r] * s4[r];
                        if (diag && (sg > qg + r)) val = 0.0f;
                        const bf16 vb16 = (bf16)val;
                        z[r] += (float)vb16;           // consistent with what multiplies V
                        sSg[(row_l + r)*72 + col] = vb16;
                    }
                }

                // O += S * V
#pragma unroll
                for (int ks = 0; ks < 2; ++ks) {
                    const v8bf sa = *(const v8bf*)&sSg[(ww*16 + lr)*72 + ks*32 + quad*8];
#pragma unroll
                    for (int nd = 0; nd < 8; ++nd) {
                        const v8bf vbf = *(const v8bf*)&sVg[(nd*16 + lr)*72 + ks*32 + quad*8];
                        o[nd] = __builtin_amdgcn_mfma_f32_16x16x32_bf16(sa, vbf, o[nd], 0, 0, 0);
                    }
                }
            }

            if (ich + 2 < nch) {
#pragma unroll
                for (int p = 0; p < 4; ++p) { curK[p] = nxtK[p]; curV[p] = nxtV[p]; }
            }
        }

        // cross-group combine: group 1 dumps partial O,z; group 0 adds + epilogue.
        const int row_l = ww*16 + quad*4;
        __syncthreads();
        if (g == 1) {
#pragma unroll
            for (int nd = 0; nd < 8; ++nd)
#pragma unroll
                for (int r = 0; r < 4; ++r)
                    sO[(row_l + r)*129 + nd*16 + lr] = o[nd][r];
#pragma unroll
            for (int r = 0; r < 4; ++r)
                sZ[(row_l + r)*17 + lr] = z[r];
        }
        __syncthreads();
        if (g == 0) {
#pragma unroll
            for (int nd = 0; nd < 8; ++nd)
#pragma unroll
                for (int r = 0; r < 4; ++r)
                    o[nd][r] += sO[(row_l + r)*129 + nd*16 + lr];
#pragma unroll
            for (int r = 0; r < 4; ++r) {
                float zz = z[r] + sZ[(row_l + r)*17 + lr];
                zz += __shfl_xor(zz, 1); zz += __shfl_xor(zz, 2);
                zz += __shfl_xor(zz, 4); zz += __shfl_xor(zz, 8);
                z[r] = zz + 1e-5f;
            }
            const size_t rbase = (size_t)(tile*64 + row_l)*HIDDIM + h*HDIM;
#pragma unroll
            for (int nd = 0; nd < 8; ++nd) {
                const int col = nd*16 + lr;
#pragma unroll
                for (int r = 0; r < 4; ++r)
                    ob[rbase + (size_t)r*HIDDIM + col] = (bf16)(o[nd][r] / z[r]);
            }
        }
    }
}

extern "C" void kernel_launch(void* const* d_in, const int* in_sizes, int n_in,
                              void* d_out, int out_size, void* d_ws, size_t ws_size,
                              hipStream_t stream)
{
    const float* hs    = (const float*)d_in[0];
    const float* Wq    = (const float*)d_in[1];
    const float* Wk    = (const float*)d_in[2];
    const float* Wv    = (const float*)d_in[3];
    const float* Wo    = (const float*)d_in[4];
    const float* gamma = (const float*)d_in[5];
    const float* beta  = (const float*)d_in[6];
    float* outp = (float*)d_out;

    const size_t MAT = (size_t)TSEQ * HIDDIM;     // 4.19M elems

    // ws layout (6 bf16 slots of 8.39 MB): hs_b(0), Wcat(1-3, q/k/v contiguous),
    // Wo_b(4), vt(5). qb/kb live in d_out (dead once gemm_out overwrites it with the
    // final fp32 output). ob aliases hs_b (dead after gemm_qkv384). fmap + transpose
    // are fused into gemm_qkv384's epilogue.
    bf16* ws   = (bf16*)d_ws;
    bf16* hs_b = ws + 0*MAT;
    bf16* ob   = hs_b;                            // alias: hs_b dead after gemm_qkv384
    bf16* Wq_b = ws + 1*MAT;                      // Wcat base
    bf16* Wk_b = ws + 2*MAT;
    bf16* Wv_b = ws + 3*MAT;
    bf16* Wo_b = ws + 4*MAT;
    bf16* vt   = ws + 5*MAT;
    bf16* qb   = (bf16*)d_out;
    bf16* kb   = (bf16*)d_out + MAT;

    conv5<<<dim3(2048, 5), 256, 0, stream>>>(hs, hs_b, Wq, Wq_b, Wk, Wk_b, Wv, Wv_b, Wo, Wo_b);
    gemm_qkv384<<<dim3(16, 16), 512, 0, stream>>>(hs_b, Wq_b, qb, kb, vt, gamma, beta);
    attn<<<dim3(16, 16), 512, 0, stream>>>(qb, kb, vt, ob);
    gemm_out<<<dim3(32, 16), 256, 0, stream>>>(ob, Wo_b, outp);
}

// Round 6
// 260.293 us; speedup vs baseline: 1.1507x; 1.0248x over previous
//
#include <hip/hip_runtime.h>
#include <hip/hip_bf16.h>
#include <stdint.h>

typedef __bf16 bf16;
typedef __bf16 v8bf __attribute__((ext_vector_type(8)));
typedef __bf16 v4bf __attribute__((ext_vector_type(4)));
typedef float  v4f  __attribute__((ext_vector_type(4)));

#define TSEQ   2048
#define HIDDIM 2048
#define NHEAD  16
#define HDIM   128

// async global->LDS, 16B per lane, LDS dest = wave-uniform base + lane*16 (m97 pattern)
__device__ __forceinline__ void async16(void* lds, const void* g)
{
    __builtin_amdgcn_global_load_lds(
        (__attribute__((address_space(1))) void*)(uintptr_t)g,
        (__attribute__((address_space(3))) void*)(unsigned int)(uintptr_t)lds,
        16, 0, 0);
}

// ---------------- f32 -> bf16 bulk convert: 5 matrices of TSEQ*HIDDIM ----------------
__global__ __launch_bounds__(256) void conv5(const float* __restrict__ s0, bf16* __restrict__ d0,
                                             const float* __restrict__ s1, bf16* __restrict__ d1,
                                             const float* __restrict__ s2, bf16* __restrict__ d2,
                                             const float* __restrict__ s3, bf16* __restrict__ d3,
                                             const float* __restrict__ s4, bf16* __restrict__ d4)
{
    const float* src; bf16* dst;
    switch (blockIdx.y) {
        case 0: src = s0; dst = d0; break;
        case 1: src = s1; dst = d1; break;
        case 2: src = s2; dst = d2; break;
        case 3: src = s3; dst = d3; break;
        default: src = s4; dst = d4; break;
    }
    const size_t i = ((size_t)blockIdx.x * 256 + threadIdx.x) * 8;
    const float4 a = *(const float4*)(src + i);
    const float4 b = *(const float4*)(src + i + 4);
    v8bf o;
    o[0] = (bf16)a.x; o[1] = (bf16)a.y; o[2] = (bf16)a.z; o[3] = (bf16)a.w;
    o[4] = (bf16)b.x; o[5] = (bf16)b.y; o[6] = (bf16)b.z; o[7] = (bf16)b.w;
    *(v8bf*)(dst + i) = o;
}

// ============ 128x384-tile 6-phase NT GEMM + fused ReBased fmap + fused V-transpose ===========
// C[2048,6144] = A * Wcat^T. Grid 16x16 = 256 blocks = 1/CU. 512 thr = 8 waves (2M x 4N);
// per-wave 64 rows x {nh*128 + wn*32 + nj*16} cols (nh 0..2), acc[4][6]. BK=64, double-
// buffered 128 KiB LDS via global_load_lds. 16 MFMA/phase, counted vmcnt (never 0 in loop).
// Bank-deswizzle both-sides: slot p of a 128B row holds logical slot p ^ (row&7).
// EPILOGUE (v6): per LN head, stage the 128x128 fragment to an LDS tile (sB is dead),
// then 4 threads/row do the LN with vector reads + 2-step shfl + 16B coalesced stores.
// V heads: store transposed directly into vt[c][t] (8B stores, L2 write-combines).

#define PBAR() do { __builtin_amdgcn_sched_barrier(0); __builtin_amdgcn_s_barrier(); \
                    __builtin_amdgcn_sched_barrier(0); } while (0)

// stage one 128-row x 64-col unit (16 KB): 2 issues/thread, wave-uniform LDS base
#define STU(ldst, gsrc) do { \
    async16((ldst) + w*512,        (gsrc) + (size_t)(w*8 + (l>>3))*2048); \
    async16((ldst) + 4096 + w*512, (gsrc) + (size_t)(64 + w*8 + (l>>3))*2048); \
} while (0)

// A-frags of buffer buf -> a[0..3][0..1] (8 ds_read_b128)
#define RDA(buf) do { _Pragma("unroll") \
    for (int mi_ = 0; mi_ < 4; ++mi_) { \
        const bf16* p_ = &sA[(buf)*8192 + (wm*64 + mi_*16 + lr)*64]; \
        a[mi_][0] = *(const v8bf*)(p_ + c0); \
        a[mi_][1] = *(const v8bf*)(p_ + c1); } } while (0)

// B-frags for chunk nh of buffer buf -> b[0..1][0..1] (4 ds_read_b128)
#define RDB(buf, nh) do { _Pragma("unroll") \
    for (int nj_ = 0; nj_ < 2; ++nj_) { \
        const bf16* p_ = &sB[(buf)*24576 + ((nh)*128 + wn*32 + nj_*16 + lr)*64]; \
        b[nj_][0] = *(const v8bf*)(p_ + c0); \
        b[nj_][1] = *(const v8bf*)(p_ + c1); } } while (0)

// 16 MFMA: 4 mi x 2 nj x 2 k for column-group nh
#define MQ(nh) do { _Pragma("unroll") \
    for (int mi_ = 0; mi_ < 4; ++mi_) { _Pragma("unroll") \
        for (int nj_ = 0; nj_ < 2; ++nj_) { \
            acc[mi_][(nh)*2+nj_] = __builtin_amdgcn_mfma_f32_16x16x32_bf16( \
                a[mi_][0], b[nj_][0], acc[mi_][(nh)*2+nj_], 0, 0, 0); \
            acc[mi_][(nh)*2+nj_] = __builtin_amdgcn_mfma_f32_16x16x32_bf16( \
                a[mi_][1], b[nj_][1], acc[mi_][(nh)*2+nj_], 0, 0, 0); \
        } } } while (0)

#define VMC(n) asm volatile("s_waitcnt vmcnt(" #n ")" ::: "memory")

__global__ __launch_bounds__(512, 2) void gemm_qkv384(const bf16* __restrict__ A,
    const bf16* __restrict__ Wcat, bf16* __restrict__ qb, bf16* __restrict__ kb,
    bf16* __restrict__ vt, const float* __restrict__ gamma, const float* __restrict__ beta)
{
    __shared__ __attribute__((aligned(16))) bf16 sA[2*8192];    // 2 x 128x64 = 32 KB
    __shared__ __attribute__((aligned(16))) bf16 sB[2*24576];   // 2 x 384x64 = 96 KB
    const int n0g = blockIdx.x * 384;         // over concat(Wq,Wk,Wv) rows (6144)
    const int m0  = blockIdx.y * 128;

    const int tid = threadIdx.x, l = tid & 63, w = tid >> 6;    // 8 waves
    const int wm = w >> 2, wn = w & 3;                          // 2x4 wave grid
    const int quad = l >> 4, lr = l & 15;
    const int scol = ((l & 7) ^ ((l >> 3) & 7)) * 8;            // staged source col
    const int c0 = ((quad    ) ^ (lr & 7)) * 8;                 // read deswizzle
    const int c1 = ((quad + 4) ^ (lr & 7)) * 8;

    const bf16* Ag = A    + (size_t)m0  * 2048 + scol;
    const bf16* Bg = Wcat + (size_t)n0g * 2048 + scol;

    v4f  acc[4][6] = {};
    v8bf a[4][2], b[2][2];

    // prologue (matches steady-state issue history): A(0) B0(0) B1(0) B2(0)
    // A(1) B0(1) B1(1) = 14 issues; B2(1) is staged at Ph0 of iter 0.
    STU(&sA[0],           Ag);
    STU(&sB[0],           Bg);
    STU(&sB[8192],        Bg + (size_t)128*2048);
    STU(&sB[16384],       Bg + (size_t)256*2048);
    STU(&sA[8192],        Ag + 64);
    STU(&sB[24576],       Bg + 64);
    STU(&sB[24576+8192],  Bg + (size_t)128*2048 + 64);
    VMC(10);                                   // A(0),B0(0) landed
    __builtin_amdgcn_s_barrier();
    __builtin_amdgcn_sched_barrier(0);

#pragma unroll 1
    for (int it = 0; it < 16; ++it) {          // tiles T=2it (buf0), T+1 (buf1)
        const int k1 =  it*128 + 64;                // tile T+1 (max 1984, no wrap)
        const int k2 = (it*128 + 128) & 2047;       // tile T+2 (wrap harmless last iter)
        const int k3 = (it*128 + 192) & 2047;       // tile T+3

        // Ph0: read A,B0(buf0); stage B2(T+1)->buf1 (read Ph5: 5-phase gap)
        RDA(0); RDB(0, 0);
        STU(&sB[24576+16384], Bg + (size_t)256*2048 + k1);
        PBAR(); __builtin_amdgcn_s_setprio(1); MQ(0); __builtin_amdgcn_s_setprio(0);
        VMC(10); PBAR();
        // Ph1: read B1(buf0); stage A,B0(T+2)->buf0 (read next Ph0: 5)
        RDB(0, 1);
        STU(&sA[0], Ag + k2);
        STU(&sB[0], Bg + k2);
        PBAR(); __builtin_amdgcn_s_setprio(1); MQ(1); __builtin_amdgcn_s_setprio(0);
        VMC(12); PBAR();
        // Ph2: read B2(buf0); stage B1(T+2)->buf0 (read next Ph1: 5)
        RDB(0, 2);
        STU(&sB[8192], Bg + (size_t)128*2048 + k2);
        PBAR(); __builtin_amdgcn_s_setprio(1); MQ(2); __builtin_amdgcn_s_setprio(0);
        VMC(10); PBAR();
        // Ph3: read A,B0(buf1); stage B2(T+2)->buf0 (read next Ph2: 5)
        RDA(1); RDB(1, 0);
        STU(&sB[16384], Bg + (size_t)256*2048 + k2);
        PBAR(); __builtin_amdgcn_s_setprio(1); MQ(0); __builtin_amdgcn_s_setprio(0);
        VMC(10); PBAR();
        // Ph4: read B1(buf1); stage A,B0(T+3)->buf1 (read next Ph3: 5)
        RDB(1, 1);
        STU(&sA[8192],  Ag + k3);
        STU(&sB[24576], Bg + k3);
        PBAR(); __builtin_amdgcn_s_setprio(1); MQ(1); __builtin_amdgcn_s_setprio(0);
        VMC(12); PBAR();
        // Ph5: read B2(buf1); stage B1(T+3)->buf1 (read next Ph4: 5)
        RDB(1, 2);
        STU(&sB[24576+8192], Bg + (size_t)128*2048 + k3);
        PBAR(); __builtin_amdgcn_s_setprio(1); MQ(2); __builtin_amdgcn_s_setprio(0);
        VMC(10); PBAR();
    }
    VMC(0);                                    // drain wrap refetches
    __syncthreads();                           // all waves done -> sA/sB dead

    // ---------------- fused epilogue: LN (q/k heads) via LDS tile, V transposed ----------
    bf16* sT = sB;                             // [128][136] bf16 tile (34 KB)
    const int erow = tid >> 2;                 // 0..127 (row within block)
    const int ecol = (tid & 3) * 32;           // 4 threads/row, 32 cols each
    float gv[32], bv[32];
#pragma unroll
    for (int i = 0; i < 8; ++i) {
        *(float4*)&gv[i*4] = *(const float4*)(gamma + ecol + i*4);
        *(float4*)&bv[i*4] = *(const float4*)(beta  + ecol + i*4);
    }

#pragma unroll
    for (int nh = 0; nh < 3; ++nh) {
        const int colg0 = n0g + nh*128;
        const int which = colg0 >> 11;         // block-uniform
        if (which == 2) {
            // V head: vt[c][t], lane holds 4 consecutive t -> 8B stores
#pragma unroll
            for (int mi = 0; mi < 4; ++mi) {
                const int row = m0 + wm*64 + mi*16 + quad*4;
#pragma unroll
                for (int jj = 0; jj < 2; ++jj) {
                    const int c = (colg0 & 2047) + wn*32 + jj*16 + lr;
                    v4bf pk;
#pragma unroll
                    for (int r = 0; r < 4; ++r) pk[r] = (bf16)acc[mi][nh*2+jj][r];
                    *(v4bf*)(vt + (size_t)c*2048 + row) = pk;
                }
            }
        } else {
            // stage this head's fragments to sT (32 x ds_write_b16, ~2-way conflicts)
#pragma unroll
            for (int mi = 0; mi < 4; ++mi) {
                const int row = wm*64 + mi*16 + quad*4;
#pragma unroll
                for (int jj = 0; jj < 2; ++jj) {
                    const int col = wn*32 + jj*16 + lr;
#pragma unroll
                    for (int r = 0; r < 4; ++r)
                        sT[(row + r)*136 + col] = (bf16)acc[mi][nh*2+jj][r];
                }
            }
            __syncthreads();
            // LN: 4 threads per row (lane^1, lane^2 shfl combine)
            float x[32];
            float s = 0.f, q = 0.f;
#pragma unroll
            for (int i = 0; i < 4; ++i) {
                const v8bf v = *(const v8bf*)&sT[erow*136 + ecol + i*8];
#pragma unroll
                for (int k = 0; k < 8; ++k) {
                    const float xv = (float)v[k] * gv[i*8+k] + bv[i*8+k];
                    x[i*8+k] = xv; s += xv; q += xv*xv;
                }
            }
            s += __shfl_xor(s, 1); q += __shfl_xor(q, 1);
            s += __shfl_xor(s, 2); q += __shfl_xor(q, 2);
            const float mu = s * (1.0f/128.0f);
            float var = q * (1.0f/128.0f) - mu*mu;
            var = fmaxf(var, 0.0f);
            bf16* Cb = (which == 0) ? qb : kb;
            const float qs = (which == 0) ? 0.08838834764831845f : 1.0f; // D^-0.5 on q
            const float rstd = rsqrtf(var + 1e-5f) * qs;
            bf16* dst = Cb + (size_t)(m0 + erow)*2048 + (colg0 & 2047) + ecol;
#pragma unroll
            for (int i = 0; i < 4; ++i) {
                v8bf o;
#pragma unroll
                for (int k = 0; k < 8; ++k)
                    o[k] = (bf16)((x[i*8+k] - mu) * rstd);
                *(v8bf*)(dst + i*8) = o;
            }
            __syncthreads();                   // sT reused by next LN head
        }
    }
}

// ------- 128x64-tile NT GEMM (fp32 out): 512 blocks -> 2 blocks/CU for overlap -------
__global__ __launch_bounds__(256) void gemm_out(const bf16* __restrict__ A,
    const bf16* __restrict__ B, float* __restrict__ C)
{
    __shared__ __attribute__((aligned(16))) bf16 sA[128*32];
    __shared__ __attribute__((aligned(16))) bf16 sB[64*32];
    const int m0 = blockIdx.y * 128, n0 = blockIdx.x * 64;
    const int K = HIDDIM, ldc = HIDDIM;
    const int tid  = threadIdx.x;
    const int lane = tid & 63;
    const int w    = tid >> 6;           // wave 0..3
    const int wm   = w >> 1, wn = w & 1; // 2x2 waves of 64x32
    const int quad = lane >> 4, lr = lane & 15;
    const int srow = lane >> 2;          // staging: 16 rows x 4 lanes/row
    const int scol = (lane & 3) * 8;

    const bf16* gA0 = A + (size_t)(m0 + w*32 + srow) * K + scol;
    const bf16* gB0 = B + (size_t)(n0 + w*16 + srow) * K + scol;
    bf16* lA0 = &sA[w*1024];
    bf16* lB0 = &sB[w*512];

    v4f acc[4][2] = {};

    for (int kt = 0; kt < K; kt += 32) {
        __syncthreads();
        async16(lA0,       gA0 + kt);
        async16(lA0 + 512, gA0 + (size_t)16*K + kt);
        async16(lB0,       gB0 + kt);
        __syncthreads();
        v8bf a[4], b[2];
#pragma unroll
        for (int i = 0; i < 4; ++i)
            a[i] = *(const v8bf*)&sA[(wm*64 + i*16 + lr)*32 + quad*8];
#pragma unroll
        for (int j = 0; j < 2; ++j)
            b[j] = *(const v8bf*)&sB[(wn*32 + j*16 + lr)*32 + quad*8];
#pragma unroll
        for (int i = 0; i < 4; ++i)
#pragma unroll
            for (int j = 0; j < 2; ++j)
                acc[i][j] = __builtin_amdgcn_mfma_f32_16x16x32_bf16(a[i], b[j], acc[i][j], 0, 0, 0);
    }

#pragma unroll
    for (int i = 0; i < 4; ++i) {
        const int row_b = m0 + wm*64 + i*16 + quad*4;
#pragma unroll
        for (int j = 0; j < 2; ++j) {
            const int col = n0 + wn*32 + j*16 + lr;
#pragma unroll
            for (int r = 0; r < 4; ++r)
                C[(size_t)(row_b + r)*ldc + col] = acc[i][j][r];
        }
    }
}

// ---------------- quadratic causal attention, paired 64-row q-tiles ----------------
// Balance fix: block handles tiles (31-p) and (p) -> exactly 33 chunks per block.
// grid = 16 pairs x 16 heads = 256 blocks (1/CU), 512 threads = 8 waves.
__global__ __launch_bounds__(512, 2) void attn(const bf16* __restrict__ qb,
                                               const bf16* __restrict__ kb,
                                               const bf16* __restrict__ vt,
                                               bf16* __restrict__ ob)
{
    __shared__ __attribute__((aligned(16))) bf16 sK[2*64*136];   // per-buf [s][d], pad 8
    __shared__ __attribute__((aligned(16))) bf16 sV[2*128*72];   // per-buf [d][s], pad 8
    __shared__ __attribute__((aligned(16))) bf16 sS[2*64*72];    // per-group [q][s], pad 8
    __shared__ __attribute__((aligned(16))) float sO[64*129];    // combine scratch, pad 1
    __shared__ __attribute__((aligned(16))) float sZ[64*17];

    const int h    = blockIdx.y;
    const int pr   = blockIdx.x;              // pair index 0..15
    const int tid  = threadIdx.x, lane = tid & 63;
    const int w    = tid >> 6;                // 0..7
    const int g    = w >> 2;                  // chunk group 0/1
    const int ww   = w & 3;                   // wave within group
    const int quad = lane >> 4, lr = lane & 15;
    const int rs   = tid >> 4;                // staging row 0..31 (x4 passes)
    const int cs   = (tid & 15) * 8;          // staging col 0..120

#pragma unroll
    for (int ti = 0; ti < 2; ++ti) {
        const int tile = ti ? pr : (31 - pr);
        const int nch  = tile + 1;

        // Q fragments (A-layout): wave owns q-rows [tile*64 + ww*16, +16)
        v8bf qa[4];
        {
            const bf16* q0 = qb + (size_t)(tile*64 + ww*16 + lr)*HIDDIM + h*HDIM + quad*8;
#pragma unroll
            for (int ks = 0; ks < 4; ++ks)
                qa[ks] = *(const v8bf*)(q0 + ks*32);
        }

        v4f  o[8] = {};
        float z[4] = {0.f, 0.f, 0.f, 0.f};

        v8bf curK[4], curV[4], nxtK[4], nxtV[4];
#pragma unroll
        for (int p = 0; p < 4; ++p) {
            curK[p] = *(const v8bf*)(kb + (size_t)(rs + p*32)*HIDDIM + h*HDIM + cs);
            curV[p] = *(const v8bf*)(vt + (size_t)(h*HDIM + rs + p*32)*HIDDIM + cs);
        }

        for (int ich = 0; ich < nch; ich += 2) {
            __syncthreads();                  // prev-chunk LDS reads done
#pragma unroll
            for (int p = 0; p < 4; ++p) {
                const int r = rs + p*32;      // kv row within pair [0,128)
                *(v8bf*)&sK[(r>>6)*8704 + (r&63)*136 + cs] = curK[p];
            }
#pragma unroll
            for (int p = 0; p < 4; ++p)       // cs selects buffer (col>=64 -> buf 1)
                *(v8bf*)&sV[(cs>>6)*9216 + (rs + p*32)*72 + (cs & 63)] = curV[p];

            if (ich + 2 < nch) {              // prefetch next pair (overlaps compute)
                const int s1 = (ich + 2) * 64;
#pragma unroll
                for (int p = 0; p < 4; ++p) {
                    nxtK[p] = *(const v8bf*)(kb + (size_t)(s1 + rs + p*32)*HIDDIM + h*HDIM + cs);
                    nxtV[p] = *(const v8bf*)(vt + (size_t)(h*HDIM + rs + p*32)*HIDDIM + s1 + cs);
                }
            }
            __syncthreads();                  // tiles visible

            const int ch = ich + g;
            if (ch < nch) {
                const bf16* sKg = &sK[g*8704];
                const bf16* sVg = &sV[g*9216];
                bf16*       sSg = &sS[g*4608];
                const bool  diag = (ch == tile);
                const int   s0   = ch * 64;

                // QK^T -> square/mask -> z, sS (sS rows wave-private)
                v8bf kbf[4][4];
#pragma unroll
                for (int nj = 0; nj < 4; ++nj)
#pragma unroll
                    for (int ks = 0; ks < 4; ++ks)
                        kbf[nj][ks] = *(const v8bf*)&sKg[(nj*16 + lr)*136 + ks*32 + quad*8];
                const int row_l = ww*16 + quad*4;
                const int qg    = tile*64 + row_l;
#pragma unroll
                for (int nj = 0; nj < 4; ++nj) {
                    v4f s4 = {0.f, 0.f, 0.f, 0.f};
#pragma unroll
                    for (int ks = 0; ks < 4; ++ks)
                        s4 = __builtin_amdgcn_mfma_f32_16x16x32_bf16(qa[ks], kbf[nj][ks], s4, 0, 0, 0);
                    const int col = nj*16 + lr;
                    const int sg  = s0 + col;
#pragma unroll
                    for (int r = 0; r < 4; ++r) {
                        float val = s4[r] * s4[r];
                        if (diag && (sg > qg + r)) val = 0.0f;
                        const bf16 vb16 = (bf16)val;
                        z[r] += (float)vb16;           // consistent with what multiplies V
                        sSg[(row_l + r)*72 + col] = vb16;
                    }
                }

                // O += S * V
#pragma unroll
                for (int ks = 0; ks < 2; ++ks) {
                    const v8bf sa = *(const v8bf*)&sSg[(ww*16 + lr)*72 + ks*32 + quad*8];
#pragma unroll
                    for (int nd = 0; nd < 8; ++nd) {
                        const v8bf vbf = *(const v8bf*)&sVg[(nd*16 + lr)*72 + ks*32 + quad*8];
                        o[nd] = __builtin_amdgcn_mfma_f32_16x16x32_bf16(sa, vbf, o[nd], 0, 0, 0);
                    }
                }
            }

            if (ich + 2 < nch) {
#pragma unroll
                for (int p = 0; p < 4; ++p) { curK[p] = nxtK[p]; curV[p] = nxtV[p]; }
            }
        }

        // cross-group combine: group 1 dumps partial O,z; group 0 adds + epilogue.
        const int row_l = ww*16 + quad*4;
        __syncthreads();
        if (g == 1) {
#pragma unroll
            for (int nd = 0; nd < 8; ++nd)
#pragma unroll
                for (int r = 0; r < 4; ++r)
                    sO[(row_l + r)*129 + nd*16 + lr] = o[nd][r];
#pragma unroll
            for (int r = 0; r < 4; ++r)
                sZ[(row_l + r)*17 + lr] = z[r];
        }
        __syncthreads();
        if (g == 0) {
#pragma unroll
            for (int nd = 0; nd < 8; ++nd)
#pragma unroll
                for (int r = 0; r < 4; ++r)
                    o[nd][r] += sO[(row_l + r)*129 + nd*16 + lr];
#pragma unroll
            for (int r = 0; r < 4; ++r) {
                float zz = z[r] + sZ[(row_l + r)*17 + lr];
                zz += __shfl_xor(zz, 1); zz += __shfl_xor(zz, 2);
                zz += __shfl_xor(zz, 4); zz += __shfl_xor(zz, 8);
                z[r] = zz + 1e-5f;
            }
            const size_t rbase = (size_t)(tile*64 + row_l)*HIDDIM + h*HDIM;
#pragma unroll
            for (int nd = 0; nd < 8; ++nd) {
                const int col = nd*16 + lr;
#pragma unroll
                for (int r = 0; r < 4; ++r)
                    ob[rbase + (size_t)r*HIDDIM + col] = (bf16)(o[nd][r] / z[r]);
            }
        }
    }
}

extern "C" void kernel_launch(void* const* d_in, const int* in_sizes, int n_in,
                              void* d_out, int out_size, void* d_ws, size_t ws_size,
                              hipStream_t stream)
{
    const float* hs    = (const float*)d_in[0];
    const float* Wq    = (const float*)d_in[1];
    const float* Wk    = (const float*)d_in[2];
    const float* Wv    = (const float*)d_in[3];
    const float* Wo    = (const float*)d_in[4];
    const float* gamma = (const float*)d_in[5];
    const float* beta  = (const float*)d_in[6];
    float* outp = (float*)d_out;

    const size_t MAT = (size_t)TSEQ * HIDDIM;     // 4.19M elems

    // ws layout (6 bf16 slots of 8.39 MB): hs_b(0), Wcat(1-3, q/k/v contiguous),
    // Wo_b(4), vt(5). qb/kb live in d_out (dead once gemm_out overwrites it with the
    // final fp32 output). ob aliases hs_b (dead after gemm_qkv384). fmap + transpose
    // are fused into gemm_qkv384's epilogue.
    bf16* ws   = (bf16*)d_ws;
    bf16* hs_b = ws + 0*MAT;
    bf16* ob   = hs_b;                            // alias: hs_b dead after gemm_qkv384
    bf16* Wq_b = ws + 1*MAT;                      // Wcat base
    bf16* Wk_b = ws + 2*MAT;
    bf16* Wv_b = ws + 3*MAT;
    bf16* Wo_b = ws + 4*MAT;
    bf16* vt   = ws + 5*MAT;
    bf16* qb   = (bf16*)d_out;
    bf16* kb   = (bf16*)d_out + MAT;

    conv5<<<dim3(2048, 5), 256, 0, stream>>>(hs, hs_b, Wq, Wq_b, Wk, Wk_b, Wv, Wv_b, Wo, Wo_b);
    gemm_qkv384<<<dim3(16, 16), 512, 0, stream>>>(hs_b, Wq_b, qb, kb, vt, gamma, beta);
    attn<<<dim3(16, 16), 512, 0, stream>>>(qb, kb, vt, ob);
    gemm_out<<<dim3(32, 16), 256, 0, stream>>>(ob, Wo_b, outp);
}

// Round 7
// 246.404 us; speedup vs baseline: 1.2156x; 1.0564x over previous
//
#include <hip/hip_runtime.h>
#include <hip/hip_bf16.h>
#include <stdint.h>

typedef __bf16 bf16;
typedef __bf16 v8bf __attribute__((ext_vector_type(8)));
typedef __bf16 v4bf __attribute__((ext_vector_type(4)));
typedef float  v4f  __attribute__((ext_vector_type(4)));

#define TSEQ   2048
#define HIDDIM 2048
#define NHEAD  16
#define HDIM   128

// async global->LDS, 16B per lane, LDS dest = wave-uniform base + lane*16 (m97 pattern)
__device__ __forceinline__ void async16(void* lds, const void* g)
{
    __builtin_amdgcn_global_load_lds(
        (__attribute__((address_space(1))) void*)(uintptr_t)g,
        (__attribute__((address_space(3))) void*)(unsigned int)(uintptr_t)lds,
        16, 0, 0);
}

// ---------------- f32 -> bf16 bulk convert: 5 matrices of TSEQ*HIDDIM ----------------
__global__ __launch_bounds__(256) void conv5(const float* __restrict__ s0, bf16* __restrict__ d0,
                                             const float* __restrict__ s1, bf16* __restrict__ d1,
                                             const float* __restrict__ s2, bf16* __restrict__ d2,
                                             const float* __restrict__ s3, bf16* __restrict__ d3,
                                             const float* __restrict__ s4, bf16* __restrict__ d4)
{
    const float* src; bf16* dst;
    switch (blockIdx.y) {
        case 0: src = s0; dst = d0; break;
        case 1: src = s1; dst = d1; break;
        case 2: src = s2; dst = d2; break;
        case 3: src = s3; dst = d3; break;
        default: src = s4; dst = d4; break;
    }
    const size_t i = ((size_t)blockIdx.x * 256 + threadIdx.x) * 8;
    const float4 a = *(const float4*)(src + i);
    const float4 b = *(const float4*)(src + i + 4);
    v8bf o;
    o[0] = (bf16)a.x; o[1] = (bf16)a.y; o[2] = (bf16)a.z; o[3] = (bf16)a.w;
    o[4] = (bf16)b.x; o[5] = (bf16)b.y; o[6] = (bf16)b.z; o[7] = (bf16)b.w;
    *(v8bf*)(dst + i) = o;
}

// ============ 128x384-tile 6-phase NT GEMM + fused ReBased fmap + fused V-transpose ===========
// C[2048,6144] = A * Wcat^T. Grid 16x16 = 256 blocks = 1/CU. 512 thr = 8 waves (2M x 4N);
// per-wave 64 rows x {nh*128 + wn*32 + nj*16} cols (nh 0..2), acc[4][6]. BK=64, double-
// buffered 128 KiB LDS via global_load_lds. 16 MFMA/phase, counted vmcnt (never 0 in loop).
// Bank-deswizzle both-sides: slot p of a 128B row holds logical slot p ^ (row&7).
// EPILOGUE: per LN head, stage the 128x128 fragment to an LDS tile (sB is dead),
// then 4 threads/row do the LN with vector reads + 2-step shfl + 16B coalesced stores.
// V heads: store transposed directly into vt[c][t] (8B stores, L2 write-combines).

#define PBAR() do { __builtin_amdgcn_sched_barrier(0); __builtin_amdgcn_s_barrier(); \
                    __builtin_amdgcn_sched_barrier(0); } while (0)

// stage one 128-row x 64-col unit (16 KB): 2 issues/thread, wave-uniform LDS base
#define STU(ldst, gsrc) do { \
    async16((ldst) + w*512,        (gsrc) + (size_t)(w*8 + (l>>3))*2048); \
    async16((ldst) + 4096 + w*512, (gsrc) + (size_t)(64 + w*8 + (l>>3))*2048); \
} while (0)

// A-frags of buffer buf -> a[0..3][0..1] (8 ds_read_b128)
#define RDA(buf) do { _Pragma("unroll") \
    for (int mi_ = 0; mi_ < 4; ++mi_) { \
        const bf16* p_ = &sA[(buf)*8192 + (wm*64 + mi_*16 + lr)*64]; \
        a[mi_][0] = *(const v8bf*)(p_ + c0); \
        a[mi_][1] = *(const v8bf*)(p_ + c1); } } while (0)

// B-frags for chunk nh of buffer buf -> b[0..1][0..1] (4 ds_read_b128)
#define RDB(buf, nh) do { _Pragma("unroll") \
    for (int nj_ = 0; nj_ < 2; ++nj_) { \
        const bf16* p_ = &sB[(buf)*24576 + ((nh)*128 + wn*32 + nj_*16 + lr)*64]; \
        b[nj_][0] = *(const v8bf*)(p_ + c0); \
        b[nj_][1] = *(const v8bf*)(p_ + c1); } } while (0)

// 16 MFMA: 4 mi x 2 nj x 2 k for column-group nh
#define MQ(nh) do { _Pragma("unroll") \
    for (int mi_ = 0; mi_ < 4; ++mi_) { _Pragma("unroll") \
        for (int nj_ = 0; nj_ < 2; ++nj_) { \
            acc[mi_][(nh)*2+nj_] = __builtin_amdgcn_mfma_f32_16x16x32_bf16( \
                a[mi_][0], b[nj_][0], acc[mi_][(nh)*2+nj_], 0, 0, 0); \
            acc[mi_][(nh)*2+nj_] = __builtin_amdgcn_mfma_f32_16x16x32_bf16( \
                a[mi_][1], b[nj_][1], acc[mi_][(nh)*2+nj_], 0, 0, 0); \
        } } } while (0)

#define VMC(n) asm volatile("s_waitcnt vmcnt(" #n ")" ::: "memory")

__global__ __launch_bounds__(512, 2) void gemm_qkv384(const bf16* __restrict__ A,
    const bf16* __restrict__ Wcat, bf16* __restrict__ qb, bf16* __restrict__ kb,
    bf16* __restrict__ vt, const float* __restrict__ gamma, const float* __restrict__ beta)
{
    __shared__ __attribute__((aligned(16))) bf16 sA[2*8192];    // 2 x 128x64 = 32 KB
    __shared__ __attribute__((aligned(16))) bf16 sB[2*24576];   // 2 x 384x64 = 96 KB
    const int n0g = blockIdx.x * 384;         // over concat(Wq,Wk,Wv) rows (6144)
    const int m0  = blockIdx.y * 128;

    const int tid = threadIdx.x, l = tid & 63, w = tid >> 6;    // 8 waves
    const int wm = w >> 2, wn = w & 3;                          // 2x4 wave grid
    const int quad = l >> 4, lr = l & 15;
    const int scol = ((l & 7) ^ ((l >> 3) & 7)) * 8;            // staged source col
    const int c0 = ((quad    ) ^ (lr & 7)) * 8;                 // read deswizzle
    const int c1 = ((quad + 4) ^ (lr & 7)) * 8;

    const bf16* Ag = A    + (size_t)m0  * 2048 + scol;
    const bf16* Bg = Wcat + (size_t)n0g * 2048 + scol;

    v4f  acc[4][6] = {};
    v8bf a[4][2], b[2][2];

    // prologue (matches steady-state issue history): A(0) B0(0) B1(0) B2(0)
    // A(1) B0(1) B1(1) = 14 issues; B2(1) is staged at Ph0 of iter 0.
    STU(&sA[0],           Ag);
    STU(&sB[0],           Bg);
    STU(&sB[8192],        Bg + (size_t)128*2048);
    STU(&sB[16384],       Bg + (size_t)256*2048);
    STU(&sA[8192],        Ag + 64);
    STU(&sB[24576],       Bg + 64);
    STU(&sB[24576+8192],  Bg + (size_t)128*2048 + 64);
    VMC(10);                                   // A(0),B0(0) landed
    __builtin_amdgcn_s_barrier();
    __builtin_amdgcn_sched_barrier(0);

#pragma unroll 1
    for (int it = 0; it < 16; ++it) {          // tiles T=2it (buf0), T+1 (buf1)
        const int k1 =  it*128 + 64;                // tile T+1 (max 1984, no wrap)
        const int k2 = (it*128 + 128) & 2047;       // tile T+2 (wrap harmless last iter)
        const int k3 = (it*128 + 192) & 2047;       // tile T+3

        // Ph0: read A,B0(buf0); stage B2(T+1)->buf1 (read Ph5: 5-phase gap)
        RDA(0); RDB(0, 0);
        STU(&sB[24576+16384], Bg + (size_t)256*2048 + k1);
        PBAR(); __builtin_amdgcn_s_setprio(1); MQ(0); __builtin_amdgcn_s_setprio(0);
        VMC(10); PBAR();
        // Ph1: read B1(buf0); stage A,B0(T+2)->buf0 (read next Ph0: 5)
        RDB(0, 1);
        STU(&sA[0], Ag + k2);
        STU(&sB[0], Bg + k2);
        PBAR(); __builtin_amdgcn_s_setprio(1); MQ(1); __builtin_amdgcn_s_setprio(0);
        VMC(12); PBAR();
        // Ph2: read B2(buf0); stage B1(T+2)->buf0 (read next Ph1: 5)
        RDB(0, 2);
        STU(&sB[8192], Bg + (size_t)128*2048 + k2);
        PBAR(); __builtin_amdgcn_s_setprio(1); MQ(2); __builtin_amdgcn_s_setprio(0);
        VMC(10); PBAR();
        // Ph3: read A,B0(buf1); stage B2(T+2)->buf0 (read next Ph2: 5)
        RDA(1); RDB(1, 0);
        STU(&sB[16384], Bg + (size_t)256*2048 + k2);
        PBAR(); __builtin_amdgcn_s_setprio(1); MQ(0); __builtin_amdgcn_s_setprio(0);
        VMC(10); PBAR();
        // Ph4: read B1(buf1); stage A,B0(T+3)->buf1 (read next Ph3: 5)
        RDB(1, 1);
        STU(&sA[8192],  Ag + k3);
        STU(&sB[24576], Bg + k3);
        PBAR(); __builtin_amdgcn_s_setprio(1); MQ(1); __builtin_amdgcn_s_setprio(0);
        VMC(12); PBAR();
        // Ph5: read B2(buf1); stage B1(T+3)->buf1 (read next Ph4: 5)
        RDB(1, 2);
        STU(&sB[24576+8192], Bg + (size_t)128*2048 + k3);
        PBAR(); __builtin_amdgcn_s_setprio(1); MQ(2); __builtin_amdgcn_s_setprio(0);
        VMC(10); PBAR();
    }
    VMC(0);                                    // drain wrap refetches
    __syncthreads();                           // all waves done -> sA/sB dead

    // ---------------- fused epilogue: LN (q/k heads) via LDS tile, V transposed ----------
    bf16* sT = sB;                             // [128][136] bf16 tile (34 KB)
    const int erow = tid >> 2;                 // 0..127 (row within block)
    const int ecol = (tid & 3) * 32;           // 4 threads/row, 32 cols each
    float gv[32], bv[32];
#pragma unroll
    for (int i = 0; i < 8; ++i) {
        *(float4*)&gv[i*4] = *(const float4*)(gamma + ecol + i*4);
        *(float4*)&bv[i*4] = *(const float4*)(beta  + ecol + i*4);
    }

#pragma unroll
    for (int nh = 0; nh < 3; ++nh) {
        const int colg0 = n0g + nh*128;
        const int which = colg0 >> 11;         // block-uniform
        if (which == 2) {
            // V head: vt[c][t], lane holds 4 consecutive t -> 8B stores
#pragma unroll
            for (int mi = 0; mi < 4; ++mi) {
                const int row = m0 + wm*64 + mi*16 + quad*4;
#pragma unroll
                for (int jj = 0; jj < 2; ++jj) {
                    const int c = (colg0 & 2047) + wn*32 + jj*16 + lr;
                    v4bf pk;
#pragma unroll
                    for (int r = 0; r < 4; ++r) pk[r] = (bf16)acc[mi][nh*2+jj][r];
                    *(v4bf*)(vt + (size_t)c*2048 + row) = pk;
                }
            }
        } else {
            // stage this head's fragments to sT (32 x ds_write_b16, ~2-way conflicts)
#pragma unroll
            for (int mi = 0; mi < 4; ++mi) {
                const int row = wm*64 + mi*16 + quad*4;
#pragma unroll
                for (int jj = 0; jj < 2; ++jj) {
                    const int col = wn*32 + jj*16 + lr;
#pragma unroll
                    for (int r = 0; r < 4; ++r)
                        sT[(row + r)*136 + col] = (bf16)acc[mi][nh*2+jj][r];
                }
            }
            __syncthreads();
            // LN: 4 threads per row (lane^1, lane^2 shfl combine)
            float x[32];
            float s = 0.f, q = 0.f;
#pragma unroll
            for (int i = 0; i < 4; ++i) {
                const v8bf v = *(const v8bf*)&sT[erow*136 + ecol + i*8];
#pragma unroll
                for (int k = 0; k < 8; ++k) {
                    const float xv = (float)v[k] * gv[i*8+k] + bv[i*8+k];
                    x[i*8+k] = xv; s += xv; q += xv*xv;
                }
            }
            s += __shfl_xor(s, 1); q += __shfl_xor(q, 1);
            s += __shfl_xor(s, 2); q += __shfl_xor(q, 2);
            const float mu = s * (1.0f/128.0f);
            float var = q * (1.0f/128.0f) - mu*mu;
            var = fmaxf(var, 0.0f);
            bf16* Cb = (which == 0) ? qb : kb;
            const float qs = (which == 0) ? 0.08838834764831845f : 1.0f; // D^-0.5 on q
            const float rstd = rsqrtf(var + 1e-5f) * qs;
            bf16* dst = Cb + (size_t)(m0 + erow)*2048 + (colg0 & 2047) + ecol;
#pragma unroll
            for (int i = 0; i < 4; ++i) {
                v8bf o;
#pragma unroll
                for (int k = 0; k < 8; ++k)
                    o[k] = (bf16)((x[i*8+k] - mu) * rstd);
                *(v8bf*)(dst + i*8) = o;
            }
            __syncthreads();                   // sT reused by next LN head
        }
    }
}

// ======= 128x128-tile NT GEMM (fp32 out): full-chip 16x16 grid, 2-K-tiles/phase =======
// 512 thr = 8 waves (2M x 4N), per-wave 64x32, acc[4][2]. 4 LDS buffers (2 pairs) of
// 128x64 per operand; phase p reads pair (tiles 2p,2p+1) while staging the other pair
// (tiles 2p+2,2p+3). 32 MFMA/wave/phase (2x the qkv384 phase density), 16 phases.
// vmcnt(0) drain per phase is safe: issue->wait gap ~2000 cyc >> L2 latency, inputs
// are LLC-resident (17 MB). Same both-sides XOR bank-deswizzle as gemm_qkv384.

#define RDO(aa, bb, buf) do { _Pragma("unroll") \
    for (int mi_ = 0; mi_ < 4; ++mi_) { \
        const bf16* p_ = &sA[(buf)*8192 + (wm*64 + mi_*16 + lr)*64]; \
        aa[mi_][0] = *(const v8bf*)(p_ + c0); \
        aa[mi_][1] = *(const v8bf*)(p_ + c1); } \
    _Pragma("unroll") \
    for (int nj_ = 0; nj_ < 2; ++nj_) { \
        const bf16* p_ = &sB[(buf)*8192 + (wn*32 + nj_*16 + lr)*64]; \
        bb[nj_][0] = *(const v8bf*)(p_ + c0); \
        bb[nj_][1] = *(const v8bf*)(p_ + c1); } } while (0)

#define MQO(aa, bb) do { _Pragma("unroll") \
    for (int mi_ = 0; mi_ < 4; ++mi_) { _Pragma("unroll") \
        for (int nj_ = 0; nj_ < 2; ++nj_) { \
            acc[mi_][nj_] = __builtin_amdgcn_mfma_f32_16x16x32_bf16( \
                aa[mi_][0], bb[nj_][0], acc[mi_][nj_], 0, 0, 0); \
            acc[mi_][nj_] = __builtin_amdgcn_mfma_f32_16x16x32_bf16( \
                aa[mi_][1], bb[nj_][1], acc[mi_][nj_], 0, 0, 0); \
        } } } while (0)

__global__ __launch_bounds__(512, 2) void gemm_out(const bf16* __restrict__ A,
    const bf16* __restrict__ B, float* __restrict__ C)
{
    __shared__ __attribute__((aligned(16))) bf16 sA[4*8192];   // 64 KB: buf t&3 of 128x64
    __shared__ __attribute__((aligned(16))) bf16 sB[4*8192];   // 64 KB
    const int m0 = blockIdx.y * 128, n0 = blockIdx.x * 128;
    const int tid = threadIdx.x, l = tid & 63, w = tid >> 6;   // 8 waves
    const int wm = w >> 2, wn = w & 3;                         // 2x4 wave grid
    const int quad = l >> 4, lr = l & 15;
    const int scol = ((l & 7) ^ ((l >> 3) & 7)) * 8;           // staged source col
    const int c0 = ((quad    ) ^ (lr & 7)) * 8;                // read deswizzle
    const int c1 = ((quad + 4) ^ (lr & 7)) * 8;

    const bf16* Ag = A + (size_t)m0 * 2048 + scol;
    const bf16* Bg = B + (size_t)n0 * 2048 + scol;

    v4f  acc[4][2] = {};
    v8bf a0[4][2], b0[2][2], a1[4][2], b1[2][2];

    // prologue: tiles 0,1 -> bufs 0,1
    STU(&sA[0],    Ag);      STU(&sB[0],    Bg);
    STU(&sA[8192], Ag + 64); STU(&sB[8192], Bg + 64);
    VMC(0);
    __builtin_amdgcn_s_barrier();
    __builtin_amdgcn_sched_barrier(0);

#pragma unroll 2
    for (int p = 0; p < 16; ++p) {
        const int e = (p & 1) * 2;                 // read pair base buf (0 or 2)
        const int o = 2 - e;                       // stage pair base buf
        const int ks0 = ((2*p + 2) & 31) * 64;     // tile 2p+2 (wrap refetch harmless)
        const int ks1 = ((2*p + 3) & 31) * 64;     // tile 2p+3
        RDO(a0, b0, e);
        RDO(a1, b1, e + 1);
        STU(&sA[o*8192],       Ag + ks0);  STU(&sB[o*8192],       Bg + ks0);
        STU(&sA[(o+1)*8192],   Ag + ks1);  STU(&sB[(o+1)*8192],   Bg + ks1);
        PBAR();
        __builtin_amdgcn_s_setprio(1);
        MQO(a0, b0);
        MQO(a1, b1);
        __builtin_amdgcn_s_setprio(0);
        VMC(0);
        PBAR();
    }

#pragma unroll
    for (int mi = 0; mi < 4; ++mi) {
        const int row = m0 + wm*64 + mi*16 + quad*4;
#pragma unroll
        for (int nj = 0; nj < 2; ++nj) {
            const int col = n0 + wn*32 + nj*16 + lr;
#pragma unroll
            for (int r = 0; r < 4; ++r)
                C[(size_t)(row + r)*HIDDIM + col] = acc[mi][nj][r];
        }
    }
}

// ---------------- quadratic causal attention, paired 64-row q-tiles ----------------
// Balance fix: block handles tiles (31-p) and (p) -> exactly 33 chunks per block.
// grid = 16 pairs x 16 heads = 256 blocks (1/CU), 512 threads = 8 waves.
__global__ __launch_bounds__(512, 2) void attn(const bf16* __restrict__ qb,
                                               const bf16* __restrict__ kb,
                                               const bf16* __restrict__ vt,
                                               bf16* __restrict__ ob)
{
    __shared__ __attribute__((aligned(16))) bf16 sK[2*64*136];   // per-buf [s][d], pad 8
    __shared__ __attribute__((aligned(16))) bf16 sV[2*128*72];   // per-buf [d][s], pad 8
    __shared__ __attribute__((aligned(16))) bf16 sS[2*64*72];    // per-group [q][s], pad 8
    __shared__ __attribute__((aligned(16))) float sO[64*129];    // combine scratch, pad 1
    __shared__ __attribute__((aligned(16))) float sZ[64*17];

    const int h    = blockIdx.y;
    const int pr   = blockIdx.x;              // pair index 0..15
    const int tid  = threadIdx.x, lane = tid & 63;
    const int w    = tid >> 6;                // 0..7
    const int g    = w >> 2;                  // chunk group 0/1
    const int ww   = w & 3;                   // wave within group
    const int quad = lane >> 4, lr = lane & 15;
    const int rs   = tid >> 4;                // staging row 0..31 (x4 passes)
    const int cs   = (tid & 15) * 8;          // staging col 0..120

#pragma unroll
    for (int ti = 0; ti < 2; ++ti) {
        const int tile = ti ? pr : (31 - pr);
        const int nch  = tile + 1;

        // Q fragments (A-layout): wave owns q-rows [tile*64 + ww*16, +16)
        v8bf qa[4];
        {
            const bf16* q0 = qb + (size_t)(tile*64 + ww*16 + lr)*HIDDIM + h*HDIM + quad*8;
#pragma unroll
            for (int ks = 0; ks < 4; ++ks)
                qa[ks] = *(const v8bf*)(q0 + ks*32);
        }

        v4f  o[8] = {};
        float z[4] = {0.f, 0.f, 0.f, 0.f};

        v8bf curK[4], curV[4], nxtK[4], nxtV[4];
#pragma unroll
        for (int p = 0; p < 4; ++p) {
            curK[p] = *(const v8bf*)(kb + (size_t)(rs + p*32)*HIDDIM + h*HDIM + cs);
            curV[p] = *(const v8bf*)(vt + (size_t)(h*HDIM + rs + p*32)*HIDDIM + cs);
        }

        for (int ich = 0; ich < nch; ich += 2) {
            __syncthreads();                  // prev-chunk LDS reads done
#pragma unroll
            for (int p = 0; p < 4; ++p) {
                const int r = rs + p*32;      // kv row within pair [0,128)
                *(v8bf*)&sK[(r>>6)*8704 + (r&63)*136 + cs] = curK[p];
            }
#pragma unroll
            for (int p = 0; p < 4; ++p)       // cs selects buffer (col>=64 -> buf 1)
                *(v8bf*)&sV[(cs>>6)*9216 + (rs + p*32)*72 + (cs & 63)] = curV[p];

            if (ich + 2 < nch) {              // prefetch next pair (overlaps compute)
                const int s1 = (ich + 2) * 64;
#pragma unroll
                for (int p = 0; p < 4; ++p) {
                    nxtK[p] = *(const v8bf*)(kb + (size_t)(s1 + rs + p*32)*HIDDIM + h*HDIM + cs);
                    nxtV[p] = *(const v8bf*)(vt + (size_t)(h*HDIM + rs + p*32)*HIDDIM + s1 + cs);
                }
            }
            __syncthreads();                  // tiles visible

            const int ch = ich + g;
            if (ch < nch) {
                const bf16* sKg = &sK[g*8704];
                const bf16* sVg = &sV[g*9216];
                bf16*       sSg = &sS[g*4608];
                const bool  diag = (ch == tile);
                const int   s0   = ch * 64;

                // QK^T -> square/mask -> z, sS (sS rows wave-private)
                v8bf kbf[4][4];
#pragma unroll
                for (int nj = 0; nj < 4; ++nj)
#pragma unroll
                    for (int ks = 0; ks < 4; ++ks)
                        kbf[nj][ks] = *(const v8bf*)&sKg[(nj*16 + lr)*136 + ks*32 + quad*8];
                const int row_l = ww*16 + quad*4;
                const int qg    = tile*64 + row_l;
#pragma unroll
                for (int nj = 0; nj < 4; ++nj) {
                    v4f s4 = {0.f, 0.f, 0.f, 0.f};
#pragma unroll
                    for (int ks = 0; ks < 4; ++ks)
                        s4 = __builtin_amdgcn_mfma_f32_16x16x32_bf16(qa[ks], kbf[nj][ks], s4, 0, 0, 0);
                    const int col = nj*16 + lr;
                    const int sg  = s0 + col;
#pragma unroll
                    for (int r = 0; r < 4; ++r) {
                        float val = s4[r] * s4[r];
                        if (diag && (sg > qg + r)) val = 0.0f;
                        const bf16 vb16 = (bf16)val;
                        z[r] += (float)vb16;           // consistent with what multiplies V
                        sSg[(row_l + r)*72 + col] = vb16;
                    }
                }

                // O += S * V
#pragma unroll
                for (int ks = 0; ks < 2; ++ks) {
                    const v8bf sa = *(const v8bf*)&sSg[(ww*16 + lr)*72 + ks*32 + quad*8];
#pragma unroll
                    for (int nd = 0; nd < 8; ++nd) {
                        const v8bf vbf = *(const v8bf*)&sVg[(nd*16 + lr)*72 + ks*32 + quad*8];
                        o[nd] = __builtin_amdgcn_mfma_f32_16x16x32_bf16(sa, vbf, o[nd], 0, 0, 0);
                    }
                }
            }

            if (ich + 2 < nch) {
#pragma unroll
                for (int p = 0; p < 4; ++p) { curK[p] = nxtK[p]; curV[p] = nxtV[p]; }
            }
        }

        // cross-group combine: group 1 dumps partial O,z; group 0 adds + epilogue.
        const int row_l = ww*16 + quad*4;
        __syncthreads();
        if (g == 1) {
#pragma unroll
            for (int nd = 0; nd < 8; ++nd)
#pragma unroll
                for (int r = 0; r < 4; ++r)
                    sO[(row_l + r)*129 + nd*16 + lr] = o[nd][r];
#pragma unroll
            for (int r = 0; r < 4; ++r)
                sZ[(row_l + r)*17 + lr] = z[r];
        }
        __syncthreads();
        if (g == 0) {
#pragma unroll
            for (int nd = 0; nd < 8; ++nd)
#pragma unroll
                for (int r = 0; r < 4; ++r)
                    o[nd][r] += sO[(row_l + r)*129 + nd*16 + lr];
#pragma unroll
            for (int r = 0; r < 4; ++r) {
                float zz = z[r] + sZ[(row_l + r)*17 + lr];
                zz += __shfl_xor(zz, 1); zz += __shfl_xor(zz, 2);
                zz += __shfl_xor(zz, 4); zz += __shfl_xor(zz, 8);
                z[r] = zz + 1e-5f;
            }
            const size_t rbase = (size_t)(tile*64 + row_l)*HIDDIM + h*HDIM;
#pragma unroll
            for (int nd = 0; nd < 8; ++nd) {
                const int col = nd*16 + lr;
#pragma unroll
                for (int r = 0; r < 4; ++r)
                    ob[rbase + (size_t)r*HIDDIM + col] = (bf16)(o[nd][r] / z[r]);
            }
        }
    }
}

extern "C" void kernel_launch(void* const* d_in, const int* in_sizes, int n_in,
                              void* d_out, int out_size, void* d_ws, size_t ws_size,
                              hipStream_t stream)
{
    const float* hs    = (const float*)d_in[0];
    const float* Wq    = (const float*)d_in[1];
    const float* Wk    = (const float*)d_in[2];
    const float* Wv    = (const float*)d_in[3];
    const float* Wo    = (const float*)d_in[4];
    const float* gamma = (const float*)d_in[5];
    const float* beta  = (const float*)d_in[6];
    float* outp = (float*)d_out;

    const size_t MAT = (size_t)TSEQ * HIDDIM;     // 4.19M elems

    // ws layout (6 bf16 slots of 8.39 MB): hs_b(0), Wcat(1-3, q/k/v contiguous),
    // Wo_b(4), vt(5). qb/kb live in d_out (dead once gemm_out overwrites it with the
    // final fp32 output). ob aliases hs_b (dead after gemm_qkv384). fmap + transpose
    // are fused into gemm_qkv384's epilogue.
    bf16* ws   = (bf16*)d_ws;
    bf16* hs_b = ws + 0*MAT;
    bf16* ob   = hs_b;                            // alias: hs_b dead after gemm_qkv384
    bf16* Wq_b = ws + 1*MAT;                      // Wcat base
    bf16* Wk_b = ws + 2*MAT;
    bf16* Wv_b = ws + 3*MAT;
    bf16* Wo_b = ws + 4*MAT;
    bf16* vt   = ws + 5*MAT;
    bf16* qb   = (bf16*)d_out;
    bf16* kb   = (bf16*)d_out + MAT;

    conv5<<<dim3(2048, 5), 256, 0, stream>>>(hs, hs_b, Wq, Wq_b, Wk, Wk_b, Wv, Wv_b, Wo, Wo_b);
    gemm_qkv384<<<dim3(16, 16), 512, 0, stream>>>(hs_b, Wq_b, qb, kb, vt, gamma, beta);
    attn<<<dim3(16, 16), 512, 0, stream>>>(qb, kb, vt, ob);
    gemm_out<<<dim3(16, 16), 512, 0, stream>>>(ob, Wo_b, outp);
}